// Round 8
// baseline (4997.258 us; speedup 1.0000x reference)
//
#include <hip/hip_runtime.h>
#include <cstddef>
#include <cstdio>

constexpr int NG    = 16;    // graphs
constexpr int NNODE = 96;    // nodes per graph
constexpr int TOTN  = 1536;  // NG*NNODE
constexpr int HD    = 128;   // hidden
constexpr int NEDGE = 24576;
constexpr int NLAY  = 3;
constexpr int PQS   = 132;   // padded LDS row stride (floats)

// ---------------- embeddings ----------------
__global__ void k_embed_nodes(const int* x, const float* atab, float* nodef, float* hiddenf) {
    const int v = blockIdx.x, h = threadIdx.x;  // TOTN x 128
    float s = 0.f;
    for (int c = 0; c < 9; ++c)
        s += atab[((size_t)(c * 119 + x[v * 9 + c])) * HD + h];
    nodef[(size_t)v * HD + h] = s;
    hiddenf[(size_t)v * HD + h] = 0.f;
}

__global__ void k_embed_edges(const int* ea, const float* btab, float* efts) {
    const int e = blockIdx.x, h = threadIdx.x;  // NEDGE x 128
    float s = 0.f;
    for (int c = 0; c < 3; ++c)
        s += btab[((size_t)(c * 6 + ea[e * 3 + c])) * HD + h];
    efts[(size_t)e * HD + h] = s;
}

__global__ void k_winit(int* winner) {
    winner[blockIdx.x * 256 + threadIdx.x] = -1;  // NG*NNODE*NNODE threads
}

// last-write-wins: largest edge id wins (numpy fancy-assignment semantics)
__global__ void k_winner(const int* esrc, const int* edst, int* winner) {
    const int e = blockIdx.x * 256 + threadIdx.x;  // NEDGE threads
    const int sg = esrc[e];
    const int g = sg / NNODE;
    const int li = sg - g * NNODE;
    const int lj = edst[e] - g * NNODE;
    atomicMax(&winner[((size_t)g * NNODE + li) * NNODE + lj], e);
}

// ---------------- per-node GEMMs: msg1'(+b_me+b_mg) / msg2 / o1 ----------------
__global__ void k_ngemm(const float* nodef, const float* hiddenf,
                        const float* Wm1, const float* Wm2, const float* Wo1,
                        const float* bm1, const float* bm2, const float* bme,
                        const float* bmg, const float* bo1,
                        float* msg1, float* msg2, float* o1buf, int layer) {
    __shared__ float zl[256];
    const int row = blockIdx.x;
    const int wh = blockIdx.y >> 1, s = blockIdx.y & 1, ls = layer * 2 + s;
    const int c = threadIdx.x;  // 128 threads
    zl[c] = nodef[(size_t)row * HD + c];
    zl[128 + c] = hiddenf[(size_t)row * HD + c];
    __syncthreads();
    const float* W;
    float* out;
    float bias;
    if (wh == 0) {
        W = Wm1 + (size_t)ls * 256 * HD;
        out = msg1 + (size_t)s * TOTN * HD;
        bias = bm1[ls * HD + c] + bme[ls * HD + c] + bmg[ls * HD + c];
    } else if (wh == 1) {
        W = Wm2 + (size_t)ls * 256 * HD;
        out = msg2 + (size_t)s * TOTN * HD;
        bias = bm2[ls * HD + c];
    } else {
        W = Wo1 + (size_t)ls * 256 * HD;
        out = o1buf + (size_t)s * TOTN * HD;
        bias = bo1[ls * HD + c];
    }
    float acc = bias;
    for (int k = 0; k < 256; ++k)
        acc += zl[k] * W[(size_t)k * HD + c];
    out[(size_t)row * HD + c] = acc;
}

// ---------------- per-edge GEMM (no bias; b_me folded into msg1) ----------------
__global__ void k_egemm(const float* efts, const float* Wme, float* emsg, int layer) {
    __shared__ float el[128];
    const int e = blockIdx.x, s = blockIdx.y, ls = layer * 2 + s, c = threadIdx.x;
    el[c] = efts[(size_t)e * HD + c];
    __syncthreads();
    const float* W = Wme + (size_t)ls * HD * HD;
    float acc = 0.f;
    for (int k = 0; k < HD; ++k)
        acc += el[k] * W[(size_t)k * HD + c];
    emsg[((size_t)s * NEDGE + e) * HD + c] = acc;
}

// ---------------- fused pair MLP + running max over senders ----------------
// grid (6 j-tiles, NG, 4={chunk,stream}); 256 thr; thread = (j-local, col-group of 8).
__global__ __launch_bounds__(256) void k_pairs(
    const float* msg1, const float* msg2, const float* emsg, const int* winner,
    const float* Wmlp1, const float* bmlp1, const float* Wmlp2, const float* bmlp2,
    float* maxpart, int layer) {
    __shared__ float Pl[16 * PQS];
    __shared__ float Ql[16 * PQS];
    const int tid = threadIdx.x;
    const int jt = blockIdx.x, b = blockIdx.y, zz = blockIdx.z;
    const int chunk = zz >> 1, s = zz & 1, ls = layer * 2 + s;
    const int jl = tid >> 4;         // 0..15  local j
    const int c0 = (tid & 15) * 8;   // col group base
    const int j = jt * 16 + jl;
    const float* W1g = Wmlp1 + (size_t)ls * HD * HD;
    const float* W2g = Wmlp2 + (size_t)ls * HD * HD;
    float b1v[8], b2v[8], m1v[8], mx[8];
    const float* m1p = msg1 + ((size_t)s * TOTN + b * NNODE + j) * HD + c0;
    for (int u = 0; u < 8; ++u) {
        b1v[u] = bmlp1[ls * HD + c0 + u];
        b2v[u] = bmlp2[ls * HD + c0 + u];
        m1v[u] = m1p[u];
        mx[u] = -3.402823466e38f;
    }
    for (int it = 0; it < 48; ++it) {
        const int i = chunk * 48 + it;
        const int wv = winner[((size_t)b * NNODE + i) * NNODE + j];
        const float* m2p = msg2 + ((size_t)s * TOTN + b * NNODE + i) * HD + c0;
        float pv[8];
        for (int u = 0; u < 8; ++u) pv[u] = m1v[u] + m2p[u];
        if (wv >= 0) {
            const float* ep = emsg + ((size_t)s * NEDGE + wv) * HD + c0;
            for (int u = 0; u < 8; ++u) pv[u] += ep[u];
        }
        for (int u = 0; u < 8; ++u) Pl[jl * PQS + c0 + u] = fmaxf(pv[u], 0.f);
        __syncthreads();
        // GEMM1: Q = relu(P @ W1 + b1)
        float acc[8] = {0.f, 0.f, 0.f, 0.f, 0.f, 0.f, 0.f, 0.f};
        for (int k = 0; k < HD; ++k) {
            const float pk = Pl[jl * PQS + k];
            const float4 wa = *(const float4*)&W1g[(size_t)k * HD + c0];
            const float4 wb = *(const float4*)&W1g[(size_t)k * HD + c0 + 4];
            acc[0] += pk * wa.x; acc[1] += pk * wa.y;
            acc[2] += pk * wa.z; acc[3] += pk * wa.w;
            acc[4] += pk * wb.x; acc[5] += pk * wb.y;
            acc[6] += pk * wb.z; acc[7] += pk * wb.w;
        }
        for (int u = 0; u < 8; ++u) Ql[jl * PQS + c0 + u] = fmaxf(acc[u] + b1v[u], 0.f);
        __syncthreads();
        // GEMM2: R = Q @ W2 + b2 ; running max over i
        float acc2[8] = {0.f, 0.f, 0.f, 0.f, 0.f, 0.f, 0.f, 0.f};
        for (int k = 0; k < HD; ++k) {
            const float qk = Ql[jl * PQS + k];
            const float4 wa = *(const float4*)&W2g[(size_t)k * HD + c0];
            const float4 wb = *(const float4*)&W2g[(size_t)k * HD + c0 + 4];
            acc2[0] += qk * wa.x; acc2[1] += qk * wa.y;
            acc2[2] += qk * wa.z; acc2[3] += qk * wa.w;
            acc2[4] += qk * wb.x; acc2[5] += qk * wb.y;
            acc2[6] += qk * wb.z; acc2[7] += qk * wb.w;
        }
        for (int u = 0; u < 8; ++u) mx[u] = fmaxf(mx[u], acc2[u] + b2v[u]);
        __syncthreads();
    }
    float* op = maxpart + ((size_t)zz * TOTN + b * NNODE + j) * HD + c0;
    for (int u = 0; u < 8; ++u) op[u] = mx[u];
}

// ---------------- ret = LN(relu(o1 + maxmsg @ W_o2 + b_o2)) ----------------
__global__ void k_po(const float* maxpart, const float* o1buf,
                     const float* Wo2, const float* bo2, const float* lng, const float* lnb,
                     float* outs, int layer) {
    __shared__ float al[128];
    __shared__ float red1[128];
    __shared__ float red2[128];
    const int row = blockIdx.x, s = blockIdx.y, ls = layer * 2 + s, c = threadIdx.x;
    const float m = fmaxf(maxpart[((size_t)s * TOTN + row) * HD + c],
                          maxpart[((size_t)(2 + s) * TOTN + row) * HD + c]);
    al[c] = m;
    __syncthreads();
    const float* W = Wo2 + (size_t)ls * HD * HD;
    float acc = bo2[ls * HD + c];
    for (int k = 0; k < HD; ++k)
        acc += al[k] * W[(size_t)k * HD + c];
    const float v = fmaxf(acc + o1buf[((size_t)s * TOTN + row) * HD + c], 0.f);
    red1[c] = v;
    red2[c] = v * v;
    __syncthreads();
    for (int off = 64; off > 0; off >>= 1) {
        if (c < off) {
            red1[c] += red1[c + off];
            red2[c] += red2[c + off];
        }
        __syncthreads();
    }
    const float mean = red1[0] * (1.f / 128.f);
    float var = red2[0] * (1.f / 128.f) - mean * mean;
    var = fmaxf(var, 0.f);
    const float rstd = 1.f / sqrtf(var + 1e-5f);
    outs[(size_t)row * 256 + s * HD + c] =
        (v - mean) * rstd * lng[ls * HD + c] + lnb[ls * HD + c];
}

// ---------------- hidden = concat(outs) @ W_red + b_red ----------------
__global__ void k_red(const float* outs, const float* Wred, const float* bred,
                      float* hiddenf, int layer) {
    __shared__ float al[256];
    const int row = blockIdx.x, c = threadIdx.x;
    al[c] = outs[(size_t)row * 256 + c];
    al[128 + c] = outs[(size_t)row * 256 + 128 + c];
    __syncthreads();
    const float* W = Wred + (size_t)layer * 256 * HD;
    float acc = bred[layer * HD + c];
    for (int k = 0; k < 256; ++k)
        acc += al[k] * W[(size_t)k * HD + c];
    hiddenf[(size_t)row * HD + c] = acc;
}

// ---------------- mean-pool + 2-layer head; float32 output ----------------
__global__ void k_final(const float* hiddenf, const float* Wp1, const float* bp1,
                        const float* Wp2, const float* bp2, float* out) {
    __shared__ float se[128];
    __shared__ float sr[128];
    const int b = blockIdx.x, h = threadIdx.x;
    float acc = 0.f;
    for (int v = 0; v < NNODE; ++v)
        acc += hiddenf[((size_t)b * NNODE + v) * HD + h];
    se[h] = acc * (1.f / 96.f);
    __syncthreads();
    float a2 = bp1[h];
    for (int k = 0; k < 128; ++k)
        a2 += se[k] * Wp1[(size_t)k * HD + h];
    a2 = fmaxf(a2, 0.f);
    sr[h] = a2 * Wp2[h];
    __syncthreads();
    for (int off = 64; off > 0; off >>= 1) {
        if (h < off) sr[h] += sr[h + off];
        __syncthreads();
    }
    if (h == 0) out[b] = sr[0] + bp2[0];
}

extern "C" void kernel_launch(void* const* d_in, const int* in_sizes, int n_in,
                              void* d_out, int out_size, void* d_ws, size_t ws_size,
                              hipStream_t stream) {
    (void)in_sizes; (void)n_in; (void)out_size; (void)ws_size;
    const int* x    = (const int*)d_in[0];
    const int* ea   = (const int*)d_in[1];
    const int* esrc = (const int*)d_in[2];
    const int* edst = (const int*)d_in[3];
    const float* atab = (const float*)d_in[6];
    const float* btab = (const float*)d_in[7];
    const float* Wm1 = (const float*)d_in[8];    const float* bm1 = (const float*)d_in[9];
    const float* Wm2 = (const float*)d_in[10];   const float* bm2 = (const float*)d_in[11];
    const float* Wme = (const float*)d_in[12];   const float* bme = (const float*)d_in[13];
    const float* bmg = (const float*)d_in[15];
    const float* Wmlp1 = (const float*)d_in[16]; const float* bmlp1 = (const float*)d_in[17];
    const float* Wmlp2 = (const float*)d_in[18]; const float* bmlp2 = (const float*)d_in[19];
    const float* Wo1 = (const float*)d_in[20];   const float* bo1 = (const float*)d_in[21];
    const float* Wo2 = (const float*)d_in[22];   const float* bo2 = (const float*)d_in[23];
    const float* lng = (const float*)d_in[24];   const float* lnb = (const float*)d_in[25];
    const float* Wred = (const float*)d_in[26];  const float* bred = (const float*)d_in[27];
    const float* Wp1 = (const float*)d_in[28];   const float* bp1 = (const float*)d_in[29];
    const float* Wp2 = (const float*)d_in[30];   const float* bp2 = (const float*)d_in[31];

    char* cur = (char*)d_ws;
    float* nodef = (float*)cur;   cur += (size_t)TOTN * HD * 4;
    float* hiddenf = (float*)cur; cur += (size_t)TOTN * HD * 4;
    float* efts = (float*)cur;    cur += (size_t)NEDGE * HD * 4;
    float* emsg = (float*)cur;    cur += (size_t)2 * NEDGE * HD * 4;
    float* msg1 = (float*)cur;    cur += (size_t)2 * TOTN * HD * 4;
    float* msg2 = (float*)cur;    cur += (size_t)2 * TOTN * HD * 4;
    float* o1buf = (float*)cur;   cur += (size_t)2 * TOTN * HD * 4;
    float* maxpart = (float*)cur; cur += (size_t)4 * TOTN * HD * 4;
    float* outs = (float*)cur;    cur += (size_t)TOTN * 256 * 4;
    int* winner = (int*)cur;      cur += (size_t)NG * NNODE * NNODE * 4;

    k_winit<<<(NG * NNODE * NNODE) / 256, 256, 0, stream>>>(winner);
    k_embed_nodes<<<TOTN, 128, 0, stream>>>(x, atab, nodef, hiddenf);
    k_embed_edges<<<NEDGE, 128, 0, stream>>>(ea, btab, efts);
    k_winner<<<NEDGE / 256, 256, 0, stream>>>(esrc, edst, winner);
    for (int layer = 0; layer < NLAY; ++layer) {
        k_ngemm<<<dim3(TOTN, 6), 128, 0, stream>>>(nodef, hiddenf, Wm1, Wm2, Wo1,
                                                   bm1, bm2, bme, bmg, bo1,
                                                   msg1, msg2, o1buf, layer);
        k_egemm<<<dim3(NEDGE, 2), 128, 0, stream>>>(efts, Wme, emsg, layer);
        k_pairs<<<dim3(6, NG, 4), 256, 0, stream>>>(msg1, msg2, emsg, winner,
                                                    Wmlp1, bmlp1, Wmlp2, bmlp2,
                                                    maxpart, layer);
        k_po<<<dim3(TOTN, 2), 128, 0, stream>>>(maxpart, o1buf, Wo2, bo2, lng, lnb,
                                                outs, layer);
        k_red<<<TOTN, 128, 0, stream>>>(outs, Wred, bred, hiddenf, layer);
    }
    k_final<<<NG, 128, 0, stream>>>(hiddenf, Wp1, bp1, Wp2, bp2, (float*)d_out);

    // ---- diagnostics (capture-guarded; runs only on the correctness call) ----
    hipStreamCaptureStatus cap = hipStreamCaptureStatusNone;
    hipStreamIsCapturing(stream, &cap);
    if (cap == hipStreamCaptureStatusNone) {
        hipError_t se = hipStreamSynchronize(stream);
        float hout[16];
        hipMemcpy(hout, d_out, 64, hipMemcpyDeviceToHost);
        fprintf(stderr, "[KDIAG] sync=%s out:", hipGetErrorString(se));
        for (int i = 0; i < 16; ++i) fprintf(stderr, " %.5f", hout[i]);
        fprintf(stderr, "\n");
        fflush(stderr);
    }
}

// Round 9
// 802.698 us; speedup vs baseline: 6.2256x; 6.2256x over previous
//
#include <hip/hip_runtime.h>
#include <cstddef>

typedef _Float16 f16;
typedef f16 f16x8 __attribute__((ext_vector_type(8)));
typedef float f32x4 __attribute__((ext_vector_type(4)));

constexpr int NG    = 16;    // graphs
constexpr int NNODE = 96;    // nodes per graph
constexpr int TOTN  = 1536;  // NG*NNODE
constexpr int HD    = 128;   // hidden
constexpr int NEDGE = 24576;
constexpr int NLAY  = 3;

__device__ __forceinline__ f32x4 mfma16(f16x8 a, f16x8 b, f32x4 c) {
    return __builtin_amdgcn_mfma_f32_16x16x32_f16(a, b, c, 0, 0, 0);
}

// ---------------- embeddings ----------------
__global__ void k_embed_nodes(const int* x, const float* atab, float* nodef, float* hiddenf) {
    const int v = blockIdx.x, h = threadIdx.x;  // TOTN x 128
    float s = 0.f;
    for (int c = 0; c < 9; ++c)
        s += atab[((size_t)(c * 119 + x[v * 9 + c])) * HD + h];
    nodef[(size_t)v * HD + h] = s;
    hiddenf[(size_t)v * HD + h] = 0.f;
}

__global__ void k_embed_edges(const int* ea, const float* btab, float* efts) {
    const int e = blockIdx.x, h = threadIdx.x;  // NEDGE x 128
    float s = 0.f;
    for (int c = 0; c < 3; ++c)
        s += btab[((size_t)(c * 6 + ea[e * 3 + c])) * HD + h];
    efts[(size_t)e * HD + h] = s;
}

__global__ void k_winit(int* winner) {
    winner[blockIdx.x * 256 + threadIdx.x] = -1;  // NG*NNODE*NNODE threads
}

// last-write-wins: largest edge id wins (numpy fancy-assignment semantics)
__global__ void k_winner(const int* esrc, const int* edst, int* winner) {
    const int e = blockIdx.x * 256 + threadIdx.x;  // NEDGE threads
    const int sg = esrc[e];
    const int g = sg / NNODE;
    const int li = sg - g * NNODE;
    const int lj = edst[e] - g * NNODE;
    atomicMax(&winner[((size_t)g * NNODE + li) * NNODE + lj], e);
}

// ---------------- weight swizzle: Wmlp1/Wmlp2 -> f16 B-fragment order ----------------
// dst[mat][ ((k>>3)*128 + n)*8 + (k&7) ] = (f16) src[mat][k*128+n]
__global__ void k_wswz(const float* W1, const float* W2, f16* o1, f16* o2) {
    const int idx = blockIdx.x * 256 + threadIdx.x;  // 6*128*128 threads
    const int mat = idx >> 14;
    const int r = idx & 16383;
    const int k = r >> 7, n = r & 127;
    const size_t dst = (size_t)mat * 16384 + (((k >> 3) * 128 + n) << 3) + (k & 7);
    o1[dst] = (f16)W1[idx];
    o2[dst] = (f16)W2[idx];
}

// ---------------- per-node GEMMs: msg1'(+b_me+b_mg) / msg2 / o1 ----------------
__global__ void k_ngemm(const float* nodef, const float* hiddenf,
                        const float* Wm1, const float* Wm2, const float* Wo1,
                        const float* bm1, const float* bm2, const float* bme,
                        const float* bmg, const float* bo1,
                        float* msg1, float* msg2, float* o1buf, int layer) {
    __shared__ float zl[256];
    const int row = blockIdx.x;
    const int wh = blockIdx.y >> 1, s = blockIdx.y & 1, ls = layer * 2 + s;
    const int c = threadIdx.x;  // 128 threads
    zl[c] = nodef[(size_t)row * HD + c];
    zl[128 + c] = hiddenf[(size_t)row * HD + c];
    __syncthreads();
    const float* W;
    float* out;
    float bias;
    if (wh == 0) {
        W = Wm1 + (size_t)ls * 256 * HD;
        out = msg1 + (size_t)s * TOTN * HD;
        bias = bm1[ls * HD + c] + bme[ls * HD + c] + bmg[ls * HD + c];
    } else if (wh == 1) {
        W = Wm2 + (size_t)ls * 256 * HD;
        out = msg2 + (size_t)s * TOTN * HD;
        bias = bm2[ls * HD + c];
    } else {
        W = Wo1 + (size_t)ls * 256 * HD;
        out = o1buf + (size_t)s * TOTN * HD;
        bias = bo1[ls * HD + c];
    }
    float acc = bias;
    for (int k = 0; k < 256; ++k)
        acc += zl[k] * W[(size_t)k * HD + c];
    out[(size_t)row * HD + c] = acc;
}

// ---------------- per-edge GEMM -> f16 messages (b_me folded into msg1) ----------------
__global__ void k_egemm(const float* efts, const float* Wme, f16* emsg, int layer) {
    __shared__ float el[128];
    const int e = blockIdx.x, s = blockIdx.y, ls = layer * 2 + s, c = threadIdx.x;
    el[c] = efts[(size_t)e * HD + c];
    __syncthreads();
    const float* W = Wme + (size_t)ls * HD * HD;
    float acc = 0.f;
    for (int k = 0; k < HD; ++k)
        acc += el[k] * W[(size_t)k * HD + c];
    emsg[((size_t)s * NEDGE + e) * HD + c] = (f16)acc;
}

// ---------------- fused pair MLP (f16 MFMA) + running max over senders ----------------
// grid (6 jt, NG, 4={chunk,stream}); 256 thr. Per iter: 128 pair rows (8 i x 16 j).
// LDS: P 32KB + Q 32KB (A-fragment order). Weights from L1/L2 (pre-swizzled f16).
__global__ __launch_bounds__(256) void k_pairs(
    const float* __restrict__ msg1, const float* __restrict__ msg2,
    const f16* __restrict__ emsg, const int* __restrict__ winner,
    const f16* __restrict__ w1s, const float* __restrict__ bmlp1,
    const f16* __restrict__ w2s, const float* __restrict__ bmlp2,
    float* __restrict__ maxpart, int layer) {
    __shared__ __align__(16) f16 Pl[128 * 128];  // 32 KB  [(mt*16+kg)*16+row]*8+kj
    __shared__ __align__(16) f16 Ql[128 * 128];  // 32 KB
    const int tid = threadIdx.x, lane = tid & 63, w = tid >> 6;
    const int mr = lane & 15, q = lane >> 4;
    const int jt = blockIdx.x, b = blockIdx.y, zz = blockIdx.z;
    const int chunk = zz >> 1, s = zz & 1, ls = layer * 2 + s;
    const int j0 = jt * 16;
    const float* M1 = msg1 + ((size_t)s * TOTN + b * NNODE) * HD;
    const float* M2 = msg2 + ((size_t)s * TOTN + b * NNODE) * HD;
    const f16* EM = emsg + (size_t)s * NEDGE * HD;
    const f16* W1 = w1s + (size_t)ls * HD * HD;
    const f16* W2 = w2s + (size_t)ls * HD * HD;
    float b1c[8], b2c[8];
#pragma unroll
    for (int nt = 0; nt < 8; ++nt) {
        b1c[nt] = bmlp1[ls * HD + nt * 16 + mr];
        b2c[nt] = bmlp2[ls * HD + nt * 16 + mr];
    }
    float maxr[8][4];
#pragma unroll
    for (int nt = 0; nt < 8; ++nt)
#pragma unroll
        for (int r = 0; r < 4; ++r) maxr[nt][r] = -3.402823466e38f;

    // P-build mapping: thread -> (pair row = pii*16+pj, half of 64 cols)
    const int prow = tid >> 1, half = tid & 1;
    const int pj = prow & 15, pii = prow >> 4;  // pii 0..7
    const float* m1r = M1 + (size_t)(j0 + pj) * HD + half * 64;

    for (int it = 0; it < 6; ++it) {
        const int i = chunk * 48 + it * 8 + pii;
        const int wv = winner[((size_t)b * NNODE + i) * NNODE + (j0 + pj)];
        const float* m2r = M2 + (size_t)i * HD + half * 64;
        const f16* er = EM + (size_t)(wv < 0 ? 0 : wv) * HD + half * 64;
#pragma unroll
        for (int c8 = 0; c8 < 64; c8 += 8) {
            float4 x0 = *(const float4*)(m1r + c8);
            float4 x1 = *(const float4*)(m1r + c8 + 4);
            float4 y0 = *(const float4*)(m2r + c8);
            float4 y1 = *(const float4*)(m2r + c8 + 4);
            float v[8] = {x0.x + y0.x, x0.y + y0.y, x0.z + y0.z, x0.w + y0.w,
                          x1.x + y1.x, x1.y + y1.y, x1.z + y1.z, x1.w + y1.w};
            if (wv >= 0) {
                f16x8 e8 = *(const f16x8*)(er + c8);
#pragma unroll
                for (int u = 0; u < 8; ++u) v[u] += (float)e8[u];
            }
            f16x8 pv;
#pragma unroll
            for (int u = 0; u < 8; ++u) pv[u] = (f16)fmaxf(v[u], 0.f);
            const int k = half * 64 + c8;
            *(f16x8*)&Pl[((pii * 16 + (k >> 3)) * 16 + pj) * 8] = pv;
        }
        __syncthreads();
        // ---- GEMM1: Q = relu(P @ W1 + b1); wave w owns m-tiles 2w, 2w+1 ----
        f32x4 acc[2][8];
#pragma unroll
        for (int mt = 0; mt < 2; ++mt)
#pragma unroll
            for (int nt = 0; nt < 8; ++nt) acc[mt][nt] = (f32x4){0.f, 0.f, 0.f, 0.f};
#pragma unroll
        for (int kt = 0; kt < 4; ++kt) {
            f16x8 a0 = *(const f16x8*)&Pl[(((2 * w + 0) * 16 + kt * 4 + q) * 16 + mr) * 8];
            f16x8 a1 = *(const f16x8*)&Pl[(((2 * w + 1) * 16 + kt * 4 + q) * 16 + mr) * 8];
            const f16* bp = W1 + ((size_t)(kt * 4 + q) * HD) * 8;
#pragma unroll
            for (int nt = 0; nt < 8; ++nt) {
                f16x8 bv = *(const f16x8*)(bp + (nt * 16 + mr) * 8);
                acc[0][nt] = mfma16(a0, bv, acc[0][nt]);
                acc[1][nt] = mfma16(a1, bv, acc[1][nt]);
            }
        }
#pragma unroll
        for (int mt = 0; mt < 2; ++mt)
#pragma unroll
            for (int nt = 0; nt < 8; ++nt) {
                const int n = nt * 16 + mr;
                const int ng = nt * 2 + (mr >> 3), nj = mr & 7;
#pragma unroll
                for (int r = 0; r < 4; ++r) {
                    float v = fmaxf(acc[mt][nt][r] + b1c[nt], 0.f);
                    Ql[(((2 * w + mt) * 16 + ng) * 16 + q * 4 + r) * 8 + nj] = (f16)v;
                }
                (void)n;
            }
        __syncthreads();
        // ---- GEMM2: R = Q @ W2 + b2; running max over i (2 m-tiles = 2 i's) ----
        f32x4 ac2[2][8];
#pragma unroll
        for (int mt = 0; mt < 2; ++mt)
#pragma unroll
            for (int nt = 0; nt < 8; ++nt) ac2[mt][nt] = (f32x4){0.f, 0.f, 0.f, 0.f};
#pragma unroll
        for (int kt = 0; kt < 4; ++kt) {
            f16x8 a0 = *(const f16x8*)&Ql[(((2 * w + 0) * 16 + kt * 4 + q) * 16 + mr) * 8];
            f16x8 a1 = *(const f16x8*)&Ql[(((2 * w + 1) * 16 + kt * 4 + q) * 16 + mr) * 8];
            const f16* bp = W2 + ((size_t)(kt * 4 + q) * HD) * 8;
#pragma unroll
            for (int nt = 0; nt < 8; ++nt) {
                f16x8 bv = *(const f16x8*)(bp + (nt * 16 + mr) * 8);
                ac2[0][nt] = mfma16(a0, bv, ac2[0][nt]);
                ac2[1][nt] = mfma16(a1, bv, ac2[1][nt]);
            }
        }
#pragma unroll
        for (int nt = 0; nt < 8; ++nt)
#pragma unroll
            for (int r = 0; r < 4; ++r)
                maxr[nt][r] = fmaxf(maxr[nt][r],
                                    fmaxf(ac2[0][nt][r], ac2[1][nt][r]) + b2c[nt]);
        __syncthreads();
    }
    // ---- cross-wave max (reuse Pl as float [4][16][128]) ----
    float* red = (float*)Pl;
#pragma unroll
    for (int nt = 0; nt < 8; ++nt)
#pragma unroll
        for (int r = 0; r < 4; ++r)
            red[(w * 16 + q * 4 + r) * 128 + nt * 16 + mr] = maxr[nt][r];
    __syncthreads();
    for (int t = tid; t < 16 * 128; t += 256) {
        float m0 = fmaxf(fmaxf(red[t], red[2048 + t]), fmaxf(red[4096 + t], red[6144 + t]));
        const int jj = t >> 7, col = t & 127;
        maxpart[((size_t)zz * TOTN + b * NNODE + j0 + jj) * HD + col] = m0;
    }
}

// ---------------- ret = LN(relu(o1 + maxmsg @ W_o2 + b_o2)) ----------------
__global__ void k_po(const float* maxpart, const float* o1buf,
                     const float* Wo2, const float* bo2, const float* lng, const float* lnb,
                     float* outs, int layer) {
    __shared__ float al[128];
    __shared__ float red1[128];
    __shared__ float red2[128];
    const int row = blockIdx.x, s = blockIdx.y, ls = layer * 2 + s, c = threadIdx.x;
    const float m = fmaxf(maxpart[((size_t)s * TOTN + row) * HD + c],
                          maxpart[((size_t)(2 + s) * TOTN + row) * HD + c]);
    al[c] = m;
    __syncthreads();
    const float* W = Wo2 + (size_t)ls * HD * HD;
    float acc = bo2[ls * HD + c];
    for (int k = 0; k < HD; ++k)
        acc += al[k] * W[(size_t)k * HD + c];
    const float v = fmaxf(acc + o1buf[((size_t)s * TOTN + row) * HD + c], 0.f);
    red1[c] = v;
    red2[c] = v * v;
    __syncthreads();
    for (int off = 64; off > 0; off >>= 1) {
        if (c < off) {
            red1[c] += red1[c + off];
            red2[c] += red2[c + off];
        }
        __syncthreads();
    }
    const float mean = red1[0] * (1.f / 128.f);
    float var = red2[0] * (1.f / 128.f) - mean * mean;
    var = fmaxf(var, 0.f);
    const float rstd = 1.f / sqrtf(var + 1e-5f);
    outs[(size_t)row * 256 + s * HD + c] =
        (v - mean) * rstd * lng[ls * HD + c] + lnb[ls * HD + c];
}

// ---------------- hidden = concat(outs) @ W_red + b_red ----------------
__global__ void k_red(const float* outs, const float* Wred, const float* bred,
                      float* hiddenf, int layer) {
    __shared__ float al[256];
    const int row = blockIdx.x, c = threadIdx.x;
    al[c] = outs[(size_t)row * 256 + c];
    al[128 + c] = outs[(size_t)row * 256 + 128 + c];
    __syncthreads();
    const float* W = Wred + (size_t)layer * 256 * HD;
    float acc = bred[layer * HD + c];
    for (int k = 0; k < 256; ++k)
        acc += al[k] * W[(size_t)k * HD + c];
    hiddenf[(size_t)row * HD + c] = acc;
}

// ---------------- mean-pool + 2-layer head; float32 output ----------------
__global__ void k_final(const float* hiddenf, const float* Wp1, const float* bp1,
                        const float* Wp2, const float* bp2, float* out) {
    __shared__ float se[128];
    __shared__ float sr[128];
    const int b = blockIdx.x, h = threadIdx.x;
    float acc = 0.f;
    for (int v = 0; v < NNODE; ++v)
        acc += hiddenf[((size_t)b * NNODE + v) * HD + h];
    se[h] = acc * (1.f / 96.f);
    __syncthreads();
    float a2 = bp1[h];
    for (int k = 0; k < 128; ++k)
        a2 += se[k] * Wp1[(size_t)k * HD + h];
    a2 = fmaxf(a2, 0.f);
    sr[h] = a2 * Wp2[h];
    __syncthreads();
    for (int off = 64; off > 0; off >>= 1) {
        if (h < off) sr[h] += sr[h + off];
        __syncthreads();
    }
    if (h == 0) out[b] = sr[0] + bp2[0];
}

extern "C" void kernel_launch(void* const* d_in, const int* in_sizes, int n_in,
                              void* d_out, int out_size, void* d_ws, size_t ws_size,
                              hipStream_t stream) {
    (void)in_sizes; (void)n_in; (void)out_size; (void)ws_size;
    const int* x    = (const int*)d_in[0];
    const int* ea   = (const int*)d_in[1];
    const int* esrc = (const int*)d_in[2];
    const int* edst = (const int*)d_in[3];
    const float* atab = (const float*)d_in[6];
    const float* btab = (const float*)d_in[7];
    const float* Wm1 = (const float*)d_in[8];    const float* bm1 = (const float*)d_in[9];
    const float* Wm2 = (const float*)d_in[10];   const float* bm2 = (const float*)d_in[11];
    const float* Wme = (const float*)d_in[12];   const float* bme = (const float*)d_in[13];
    const float* bmg = (const float*)d_in[15];
    const float* Wmlp1 = (const float*)d_in[16]; const float* bmlp1 = (const float*)d_in[17];
    const float* Wmlp2 = (const float*)d_in[18]; const float* bmlp2 = (const float*)d_in[19];
    const float* Wo1 = (const float*)d_in[20];   const float* bo1 = (const float*)d_in[21];
    const float* Wo2 = (const float*)d_in[22];   const float* bo2 = (const float*)d_in[23];
    const float* lng = (const float*)d_in[24];   const float* lnb = (const float*)d_in[25];
    const float* Wred = (const float*)d_in[26];  const float* bred = (const float*)d_in[27];
    const float* Wp1 = (const float*)d_in[28];   const float* bp1 = (const float*)d_in[29];
    const float* Wp2 = (const float*)d_in[30];   const float* bp2 = (const float*)d_in[31];

    char* cur = (char*)d_ws;
    float* nodef = (float*)cur;   cur += (size_t)TOTN * HD * 4;
    float* hiddenf = (float*)cur; cur += (size_t)TOTN * HD * 4;
    float* efts = (float*)cur;    cur += (size_t)NEDGE * HD * 4;
    f16* emsg = (f16*)cur;        cur += (size_t)2 * NEDGE * HD * 2;
    float* msg1 = (float*)cur;    cur += (size_t)2 * TOTN * HD * 4;
    float* msg2 = (float*)cur;    cur += (size_t)2 * TOTN * HD * 4;
    float* o1buf = (float*)cur;   cur += (size_t)2 * TOTN * HD * 4;
    float* maxpart = (float*)cur; cur += (size_t)4 * TOTN * HD * 4;
    float* outs = (float*)cur;    cur += (size_t)TOTN * 256 * 4;
    int* winner = (int*)cur;      cur += (size_t)NG * NNODE * NNODE * 4;
    f16* w1s = (f16*)cur;         cur += (size_t)6 * HD * HD * 2;
    f16* w2s = (f16*)cur;         cur += (size_t)6 * HD * HD * 2;

    k_winit<<<(NG * NNODE * NNODE) / 256, 256, 0, stream>>>(winner);
    k_embed_nodes<<<TOTN, 128, 0, stream>>>(x, atab, nodef, hiddenf);
    k_embed_edges<<<NEDGE, 128, 0, stream>>>(ea, btab, efts);
    k_winner<<<NEDGE / 256, 256, 0, stream>>>(esrc, edst, winner);
    k_wswz<<<(6 * HD * HD) / 256, 256, 0, stream>>>(Wmlp1, Wmlp2, w1s, w2s);
    for (int layer = 0; layer < NLAY; ++layer) {
        k_ngemm<<<dim3(TOTN, 6), 128, 0, stream>>>(nodef, hiddenf, Wm1, Wm2, Wo1,
                                                   bm1, bm2, bme, bmg, bo1,
                                                   msg1, msg2, o1buf, layer);
        k_egemm<<<dim3(NEDGE, 2), 128, 0, stream>>>(efts, Wme, emsg, layer);
        k_pairs<<<dim3(6, NG, 4), 256, 0, stream>>>(msg1, msg2, emsg, winner,
                                                    w1s, bmlp1, w2s, bmlp2,
                                                    maxpart, layer);
        k_po<<<dim3(TOTN, 2), 128, 0, stream>>>(maxpart, o1buf, Wo2, bo2, lng, lnb,
                                                outs, layer);
        k_red<<<TOTN, 128, 0, stream>>>(outs, Wred, bred, hiddenf, layer);
    }
    k_final<<<NG, 128, 0, stream>>>(hiddenf, Wp1, bp1, Wp2, bp2, (float*)d_out);
}

// Round 10
// 598.378 us; speedup vs baseline: 8.3513x; 1.3415x over previous
//
#include <hip/hip_runtime.h>
#include <cstddef>

typedef _Float16 f16;
typedef f16 f16x8 __attribute__((ext_vector_type(8)));
typedef float f32x4 __attribute__((ext_vector_type(4)));

constexpr int NG    = 16;    // graphs
constexpr int NNODE = 96;    // nodes per graph
constexpr int TOTN  = 1536;  // NG*NNODE
constexpr int HD    = 128;   // hidden
constexpr int NEDGE = 24576;
constexpr int NLAY  = 3;

__device__ __forceinline__ f32x4 mfma16(f16x8 a, f16x8 b, f32x4 c) {
    return __builtin_amdgcn_mfma_f32_16x16x32_f16(a, b, c, 0, 0, 0);
}

// ---------------- embeddings ----------------
__global__ void k_embed_nodes(const int* x, const float* atab, float* nodef, float* hiddenf) {
    const int v = blockIdx.x, h = threadIdx.x;  // TOTN x 128
    float s = 0.f;
    for (int c = 0; c < 9; ++c)
        s += atab[((size_t)(c * 119 + x[v * 9 + c])) * HD + h];
    nodef[(size_t)v * HD + h] = s;
    hiddenf[(size_t)v * HD + h] = 0.f;
}

// edge embeddings straight into f16 A-fragment layout:
// eftsA[((e>>4)*16 + (h>>3))*16 + (e&15))*8 + (h&7)]
__global__ void k_embed_edges(const int* ea, const float* btab, f16* eftsA) {
    const int e = blockIdx.x, h = threadIdx.x;  // NEDGE x 128
    float s = 0.f;
    for (int c = 0; c < 3; ++c)
        s += btab[((size_t)(c * 6 + ea[e * 3 + c])) * HD + h];
    eftsA[(((size_t)(e >> 4) * 16 + (h >> 3)) * 16 + (e & 15)) * 8 + (h & 7)] = (f16)s;
}

__global__ void k_winit(int* winner) {
    winner[blockIdx.x * 256 + threadIdx.x] = -1;  // NG*NNODE*NNODE threads
}

// last-write-wins: largest edge id wins (numpy fancy-assignment semantics)
__global__ void k_winner(const int* esrc, const int* edst, int* winner) {
    const int e = blockIdx.x * 256 + threadIdx.x;  // NEDGE threads
    const int sg = esrc[e];
    const int g = sg / NNODE;
    const int li = sg - g * NNODE;
    const int lj = edst[e] - g * NNODE;
    atomicMax(&winner[((size_t)g * NNODE + li) * NNODE + lj], e);
}

// ------------- weight swizzle: Wmlp1/Wmlp2/Wme -> f16 B-fragment order -------------
// dst[mat][ ((k>>3)*128 + n)*8 + (k&7) ] = (f16) src[mat][k*128+n]   (6 mats 128x128)
__global__ void k_wswz(const float* W1, const float* W2, const float* We,
                       f16* o1, f16* o2, f16* oe) {
    const int idx = blockIdx.x * 256 + threadIdx.x;  // 6*128*128 threads
    const int mat = idx >> 14;
    const int r = idx & 16383;
    const int k = r >> 7, n = r & 127;
    const size_t dst = (size_t)mat * 16384 + (((k >> 3) * 128 + n) << 3) + (k & 7);
    o1[dst] = (f16)W1[idx];
    o2[dst] = (f16)W2[idx];
    oe[dst] = (f16)We[idx];
}

// ------- per-node GEMMs, 16-row-blocked f32: msg1'(+b_me+b_mg) / msg2 / o1 -------
__global__ __launch_bounds__(256) void k_ngemm(
    const float* nodef, const float* hiddenf,
    const float* Wm1, const float* Wm2, const float* Wo1,
    const float* bm1, const float* bm2, const float* bme,
    const float* bmg, const float* bo1,
    float* msg1, float* msg2, float* o1buf, int layer) {
    __shared__ float zl[16 * 256];  // 16 KB
    const int t0 = blockIdx.x;      // 0..95 (16-row tile)
    const int wh = blockIdx.y >> 1, s = blockIdx.y & 1, ls = layer * 2 + s;
    const int tid = threadIdx.x;
    for (int i = tid; i < 1024; i += 256) {
        const int row = i >> 6;   // 0..15
        const int c4 = i & 63;    // float4 idx over 256 cols
        float4 v;
        if (c4 < 32) v = ((const float4*)(nodef + (size_t)(t0 * 16 + row) * HD))[c4];
        else         v = ((const float4*)(hiddenf + (size_t)(t0 * 16 + row) * HD))[c4 - 32];
        ((float4*)zl)[row * 64 + c4] = v;
    }
    __syncthreads();
    const int jl = tid >> 4;          // local row 0..15
    const int c0 = (tid & 15) * 8;    // col group
    const float* W;
    float* out;
    float acc[8];
    if (wh == 0) {
        W = Wm1 + (size_t)ls * 256 * HD;
        out = msg1 + (size_t)s * TOTN * HD;
        for (int u = 0; u < 8; ++u)
            acc[u] = bm1[ls * HD + c0 + u] + bme[ls * HD + c0 + u] + bmg[ls * HD + c0 + u];
    } else if (wh == 1) {
        W = Wm2 + (size_t)ls * 256 * HD;
        out = msg2 + (size_t)s * TOTN * HD;
        for (int u = 0; u < 8; ++u) acc[u] = bm2[ls * HD + c0 + u];
    } else {
        W = Wo1 + (size_t)ls * 256 * HD;
        out = o1buf + (size_t)s * TOTN * HD;
        for (int u = 0; u < 8; ++u) acc[u] = bo1[ls * HD + c0 + u];
    }
    for (int k = 0; k < 256; ++k) {
        const float zk = zl[jl * 256 + k];
        const float4 wa = *(const float4*)&W[(size_t)k * HD + c0];
        const float4 wb = *(const float4*)&W[(size_t)k * HD + c0 + 4];
        acc[0] += zk * wa.x; acc[1] += zk * wa.y;
        acc[2] += zk * wa.z; acc[3] += zk * wa.w;
        acc[4] += zk * wb.x; acc[5] += zk * wb.y;
        acc[6] += zk * wb.z; acc[7] += zk * wb.w;
    }
    float* op = out + (size_t)(t0 * 16 + jl) * HD + c0;
    *(float4*)op = make_float4(acc[0], acc[1], acc[2], acc[3]);
    *(float4*)(op + 4) = make_float4(acc[4], acc[5], acc[6], acc[7]);
}

// ---------------- per-edge GEMM as f16 MFMA: emsg = eftsA @ Wme ----------------
// grid (192, 2); 256 thr; block = 128 edges x 128 cols, K=128.
__global__ __launch_bounds__(256) void k_egemm(
    const f16* __restrict__ eftsA, const f16* __restrict__ omes,
    f16* __restrict__ emsg, int layer) {
    const int tid = threadIdx.x, lane = tid & 63, w = tid >> 6;
    const int mr = lane & 15, q = lane >> 4;
    const int s = blockIdx.y, ls = layer * 2 + s;
    const int e0 = blockIdx.x * 128;
    const f16* B = omes + (size_t)ls * 16384;
    f32x4 acc[2][8];
#pragma unroll
    for (int mt = 0; mt < 2; ++mt)
#pragma unroll
        for (int nt = 0; nt < 8; ++nt) acc[mt][nt] = (f32x4){0.f, 0.f, 0.f, 0.f};
#pragma unroll
    for (int kt = 0; kt < 4; ++kt) {
        const int kq = kt * 4 + q;
        f16x8 a0 = *(const f16x8*)&eftsA[(((size_t)(blockIdx.x * 8 + 2 * w + 0) * 16 + kq) * 16 + mr) * 8];
        f16x8 a1 = *(const f16x8*)&eftsA[(((size_t)(blockIdx.x * 8 + 2 * w + 1) * 16 + kq) * 16 + mr) * 8];
        const f16* bp = B + ((size_t)kq * HD) * 8;
#pragma unroll
        for (int nt = 0; nt < 8; ++nt) {
            f16x8 bv = *(const f16x8*)(bp + (nt * 16 + mr) * 8);
            acc[0][nt] = mfma16(a0, bv, acc[0][nt]);
            acc[1][nt] = mfma16(a1, bv, acc[1][nt]);
        }
    }
#pragma unroll
    for (int mt = 0; mt < 2; ++mt) {
        const int ebase = e0 + (2 * w + mt) * 16 + q * 4;
#pragma unroll
        for (int nt = 0; nt < 8; ++nt) {
            const int col = nt * 16 + mr;
#pragma unroll
            for (int r = 0; r < 4; ++r)
                emsg[((size_t)s * NEDGE + ebase + r) * HD + col] = (f16)acc[mt][nt][r];
        }
    }
}

// ---------------- fused pair MLP (f16 MFMA) + running max over senders ----------------
__global__ __launch_bounds__(256) void k_pairs(
    const float* __restrict__ msg1, const float* __restrict__ msg2,
    const f16* __restrict__ emsg, const int* __restrict__ winner,
    const f16* __restrict__ w1s, const float* __restrict__ bmlp1,
    const f16* __restrict__ w2s, const float* __restrict__ bmlp2,
    float* __restrict__ maxpart, int layer) {
    __shared__ __align__(16) f16 Pl[128 * 128];  // 32 KB
    __shared__ __align__(16) f16 Ql[128 * 128];  // 32 KB
    const int tid = threadIdx.x, lane = tid & 63, w = tid >> 6;
    const int mr = lane & 15, q = lane >> 4;
    const int jt = blockIdx.x, b = blockIdx.y, zz = blockIdx.z;
    const int chunk = zz >> 1, s = zz & 1, ls = layer * 2 + s;
    const int j0 = jt * 16;
    const float* M1 = msg1 + ((size_t)s * TOTN + b * NNODE) * HD;
    const float* M2 = msg2 + ((size_t)s * TOTN + b * NNODE) * HD;
    const f16* EM = emsg + (size_t)s * NEDGE * HD;
    const f16* W1 = w1s + (size_t)ls * HD * HD;
    const f16* W2 = w2s + (size_t)ls * HD * HD;
    float b1c[8], b2c[8];
#pragma unroll
    for (int nt = 0; nt < 8; ++nt) {
        b1c[nt] = bmlp1[ls * HD + nt * 16 + mr];
        b2c[nt] = bmlp2[ls * HD + nt * 16 + mr];
    }
    float maxr[8][4];
#pragma unroll
    for (int nt = 0; nt < 8; ++nt)
#pragma unroll
        for (int r = 0; r < 4; ++r) maxr[nt][r] = -3.402823466e38f;

    const int prow = tid >> 1, half = tid & 1;
    const int pj = prow & 15, pii = prow >> 4;
    const float* m1r = M1 + (size_t)(j0 + pj) * HD + half * 64;

    for (int it = 0; it < 6; ++it) {
        const int i = chunk * 48 + it * 8 + pii;
        const int wv = winner[((size_t)b * NNODE + i) * NNODE + (j0 + pj)];
        const float* m2r = M2 + (size_t)i * HD + half * 64;
        const f16* er = EM + (size_t)(wv < 0 ? 0 : wv) * HD + half * 64;
#pragma unroll
        for (int c8 = 0; c8 < 64; c8 += 8) {
            float4 x0 = *(const float4*)(m1r + c8);
            float4 x1 = *(const float4*)(m1r + c8 + 4);
            float4 y0 = *(const float4*)(m2r + c8);
            float4 y1 = *(const float4*)(m2r + c8 + 4);
            float v[8] = {x0.x + y0.x, x0.y + y0.y, x0.z + y0.z, x0.w + y0.w,
                          x1.x + y1.x, x1.y + y1.y, x1.z + y1.z, x1.w + y1.w};
            if (wv >= 0) {
                f16x8 e8 = *(const f16x8*)(er + c8);
#pragma unroll
                for (int u = 0; u < 8; ++u) v[u] += (float)e8[u];
            }
            f16x8 pv;
#pragma unroll
            for (int u = 0; u < 8; ++u) pv[u] = (f16)fmaxf(v[u], 0.f);
            const int k = half * 64 + c8;
            *(f16x8*)&Pl[((pii * 16 + (k >> 3)) * 16 + pj) * 8] = pv;
        }
        __syncthreads();
        f32x4 acc[2][8];
#pragma unroll
        for (int mt = 0; mt < 2; ++mt)
#pragma unroll
            for (int nt = 0; nt < 8; ++nt) acc[mt][nt] = (f32x4){0.f, 0.f, 0.f, 0.f};
#pragma unroll
        for (int kt = 0; kt < 4; ++kt) {
            f16x8 a0 = *(const f16x8*)&Pl[(((2 * w + 0) * 16 + kt * 4 + q) * 16 + mr) * 8];
            f16x8 a1 = *(const f16x8*)&Pl[(((2 * w + 1) * 16 + kt * 4 + q) * 16 + mr) * 8];
            const f16* bp = W1 + ((size_t)(kt * 4 + q) * HD) * 8;
#pragma unroll
            for (int nt = 0; nt < 8; ++nt) {
                f16x8 bv = *(const f16x8*)(bp + (nt * 16 + mr) * 8);
                acc[0][nt] = mfma16(a0, bv, acc[0][nt]);
                acc[1][nt] = mfma16(a1, bv, acc[1][nt]);
            }
        }
#pragma unroll
        for (int mt = 0; mt < 2; ++mt)
#pragma unroll
            for (int nt = 0; nt < 8; ++nt) {
                const int ng = nt * 2 + (mr >> 3), nj = mr & 7;
#pragma unroll
                for (int r = 0; r < 4; ++r) {
                    float v = fmaxf(acc[mt][nt][r] + b1c[nt], 0.f);
                    Ql[(((2 * w + mt) * 16 + ng) * 16 + q * 4 + r) * 8 + nj] = (f16)v;
                }
            }
        __syncthreads();
        f32x4 ac2[2][8];
#pragma unroll
        for (int mt = 0; mt < 2; ++mt)
#pragma unroll
            for (int nt = 0; nt < 8; ++nt) ac2[mt][nt] = (f32x4){0.f, 0.f, 0.f, 0.f};
#pragma unroll
        for (int kt = 0; kt < 4; ++kt) {
            f16x8 a0 = *(const f16x8*)&Ql[(((2 * w + 0) * 16 + kt * 4 + q) * 16 + mr) * 8];
            f16x8 a1 = *(const f16x8*)&Ql[(((2 * w + 1) * 16 + kt * 4 + q) * 16 + mr) * 8];
            const f16* bp = W2 + ((size_t)(kt * 4 + q) * HD) * 8;
#pragma unroll
            for (int nt = 0; nt < 8; ++nt) {
                f16x8 bv = *(const f16x8*)(bp + (nt * 16 + mr) * 8);
                ac2[0][nt] = mfma16(a0, bv, ac2[0][nt]);
                ac2[1][nt] = mfma16(a1, bv, ac2[1][nt]);
            }
        }
#pragma unroll
        for (int nt = 0; nt < 8; ++nt)
#pragma unroll
            for (int r = 0; r < 4; ++r)
                maxr[nt][r] = fmaxf(maxr[nt][r],
                                    fmaxf(ac2[0][nt][r], ac2[1][nt][r]) + b2c[nt]);
        __syncthreads();
    }
    float* red = (float*)Pl;
#pragma unroll
    for (int nt = 0; nt < 8; ++nt)
#pragma unroll
        for (int r = 0; r < 4; ++r)
            red[(w * 16 + q * 4 + r) * 128 + nt * 16 + mr] = maxr[nt][r];
    __syncthreads();
    for (int t = tid; t < 16 * 128; t += 256) {
        float m0 = fmaxf(fmaxf(red[t], red[2048 + t]), fmaxf(red[4096 + t], red[6144 + t]));
        const int jj = t >> 7, col = t & 127;
        maxpart[((size_t)zz * TOTN + b * NNODE + j0 + jj) * HD + col] = m0;
    }
}

// ---------------- ret = LN(relu(o1 + maxmsg @ W_o2 + b_o2)) ----------------
__global__ void k_po(const float* maxpart, const float* o1buf,
                     const float* Wo2, const float* bo2, const float* lng, const float* lnb,
                     float* outs, int layer) {
    __shared__ float al[128];
    __shared__ float red1[128];
    __shared__ float red2[128];
    const int row = blockIdx.x, s = blockIdx.y, ls = layer * 2 + s, c = threadIdx.x;
    const float m = fmaxf(maxpart[((size_t)s * TOTN + row) * HD + c],
                          maxpart[((size_t)(2 + s) * TOTN + row) * HD + c]);
    al[c] = m;
    __syncthreads();
    const float* W = Wo2 + (size_t)ls * HD * HD;
    float acc = bo2[ls * HD + c];
    for (int k = 0; k < HD; ++k)
        acc += al[k] * W[(size_t)k * HD + c];
    const float v = fmaxf(acc + o1buf[((size_t)s * TOTN + row) * HD + c], 0.f);
    red1[c] = v;
    red2[c] = v * v;
    __syncthreads();
    for (int off = 64; off > 0; off >>= 1) {
        if (c < off) {
            red1[c] += red1[c + off];
            red2[c] += red2[c + off];
        }
        __syncthreads();
    }
    const float mean = red1[0] * (1.f / 128.f);
    float var = red2[0] * (1.f / 128.f) - mean * mean;
    var = fmaxf(var, 0.f);
    const float rstd = 1.f / sqrtf(var + 1e-5f);
    outs[(size_t)row * 256 + s * HD + c] =
        (v - mean) * rstd * lng[ls * HD + c] + lnb[ls * HD + c];
}

// ---------------- hidden = concat(outs) @ W_red + b_red ----------------
__global__ void k_red(const float* outs, const float* Wred, const float* bred,
                      float* hiddenf, int layer) {
    __shared__ float al[256];
    const int row = blockIdx.x, c = threadIdx.x;
    al[c] = outs[(size_t)row * 256 + c];
    al[128 + c] = outs[(size_t)row * 256 + 128 + c];
    __syncthreads();
    const float* W = Wred + (size_t)layer * 256 * HD;
    float acc = bred[layer * HD + c];
    for (int k = 0; k < 256; ++k)
        acc += al[k] * W[(size_t)k * HD + c];
    hiddenf[(size_t)row * HD + c] = acc;
}

// ---------------- mean-pool + 2-layer head; float32 output ----------------
__global__ void k_final(const float* hiddenf, const float* Wp1, const float* bp1,
                        const float* Wp2, const float* bp2, float* out) {
    __shared__ float se[128];
    __shared__ float sr[128];
    const int b = blockIdx.x, h = threadIdx.x;
    float acc = 0.f;
    for (int v = 0; v < NNODE; ++v)
        acc += hiddenf[((size_t)b * NNODE + v) * HD + h];
    se[h] = acc * (1.f / 96.f);
    __syncthreads();
    float a2 = bp1[h];
    for (int k = 0; k < 128; ++k)
        a2 += se[k] * Wp1[(size_t)k * HD + h];
    a2 = fmaxf(a2, 0.f);
    sr[h] = a2 * Wp2[h];
    __syncthreads();
    for (int off = 64; off > 0; off >>= 1) {
        if (h < off) sr[h] += sr[h + off];
        __syncthreads();
    }
    if (h == 0) out[b] = sr[0] + bp2[0];
}

extern "C" void kernel_launch(void* const* d_in, const int* in_sizes, int n_in,
                              void* d_out, int out_size, void* d_ws, size_t ws_size,
                              hipStream_t stream) {
    (void)in_sizes; (void)n_in; (void)out_size; (void)ws_size;
    const int* x    = (const int*)d_in[0];
    const int* ea   = (const int*)d_in[1];
    const int* esrc = (const int*)d_in[2];
    const int* edst = (const int*)d_in[3];
    const float* atab = (const float*)d_in[6];
    const float* btab = (const float*)d_in[7];
    const float* Wm1 = (const float*)d_in[8];    const float* bm1 = (const float*)d_in[9];
    const float* Wm2 = (const float*)d_in[10];   const float* bm2 = (const float*)d_in[11];
    const float* Wme = (const float*)d_in[12];   const float* bme = (const float*)d_in[13];
    const float* bmg = (const float*)d_in[15];
    const float* Wmlp1 = (const float*)d_in[16]; const float* bmlp1 = (const float*)d_in[17];
    const float* Wmlp2 = (const float*)d_in[18]; const float* bmlp2 = (const float*)d_in[19];
    const float* Wo1 = (const float*)d_in[20];   const float* bo1 = (const float*)d_in[21];
    const float* Wo2 = (const float*)d_in[22];   const float* bo2 = (const float*)d_in[23];
    const float* lng = (const float*)d_in[24];   const float* lnb = (const float*)d_in[25];
    const float* Wred = (const float*)d_in[26];  const float* bred = (const float*)d_in[27];
    const float* Wp1 = (const float*)d_in[28];   const float* bp1 = (const float*)d_in[29];
    const float* Wp2 = (const float*)d_in[30];   const float* bp2 = (const float*)d_in[31];

    char* cur = (char*)d_ws;
    float* nodef = (float*)cur;   cur += (size_t)TOTN * HD * 4;
    float* hiddenf = (float*)cur; cur += (size_t)TOTN * HD * 4;
    f16* eftsA = (f16*)cur;       cur += (size_t)NEDGE * HD * 2;
    f16* emsg = (f16*)cur;        cur += (size_t)2 * NEDGE * HD * 2;
    float* msg1 = (float*)cur;    cur += (size_t)2 * TOTN * HD * 4;
    float* msg2 = (float*)cur;    cur += (size_t)2 * TOTN * HD * 4;
    float* o1buf = (float*)cur;   cur += (size_t)2 * TOTN * HD * 4;
    float* maxpart = (float*)cur; cur += (size_t)4 * TOTN * HD * 4;
    float* outs = (float*)cur;    cur += (size_t)TOTN * 256 * 4;
    int* winner = (int*)cur;      cur += (size_t)NG * NNODE * NNODE * 4;
    f16* w1s = (f16*)cur;         cur += (size_t)6 * HD * HD * 2;
    f16* w2s = (f16*)cur;         cur += (size_t)6 * HD * HD * 2;
    f16* omes = (f16*)cur;        cur += (size_t)6 * HD * HD * 2;

    k_winit<<<(NG * NNODE * NNODE) / 256, 256, 0, stream>>>(winner);
    k_embed_nodes<<<TOTN, 128, 0, stream>>>(x, atab, nodef, hiddenf);
    k_embed_edges<<<NEDGE, 128, 0, stream>>>(ea, btab, eftsA);
    k_winner<<<NEDGE / 256, 256, 0, stream>>>(esrc, edst, winner);
    k_wswz<<<(6 * HD * HD) / 256, 256, 0, stream>>>(Wmlp1, Wmlp2, Wme, w1s, w2s, omes);
    for (int layer = 0; layer < NLAY; ++layer) {
        k_ngemm<<<dim3(96, 6), 256, 0, stream>>>(nodef, hiddenf, Wm1, Wm2, Wo1,
                                                 bm1, bm2, bme, bmg, bo1,
                                                 msg1, msg2, o1buf, layer);
        k_egemm<<<dim3(192, 2), 256, 0, stream>>>(eftsA, omes, emsg, layer);
        k_pairs<<<dim3(6, NG, 4), 256, 0, stream>>>(msg1, msg2, emsg, winner,
                                                    w1s, bmlp1, w2s, bmlp2,
                                                    maxpart, layer);
        k_po<<<dim3(TOTN, 2), 128, 0, stream>>>(maxpart, o1buf, Wo2, bo2, lng, lnb,
                                                outs, layer);
        k_red<<<TOTN, 128, 0, stream>>>(outs, Wred, bred, hiddenf, layer);
    }
    k_final<<<NG, 128, 0, stream>>>(hiddenf, Wp1, bp1, Wp2, bp2, (float*)d_out);
}

// Round 11
// 560.620 us; speedup vs baseline: 8.9138x; 1.0673x over previous
//
#include <hip/hip_runtime.h>
#include <cstddef>

typedef _Float16 f16;
typedef f16 f16x8 __attribute__((ext_vector_type(8)));
typedef float f32x4 __attribute__((ext_vector_type(4)));

constexpr int NG    = 16;    // graphs
constexpr int NNODE = 96;    // nodes per graph
constexpr int TOTN  = 1536;  // NG*NNODE
constexpr int HD    = 128;   // hidden
constexpr int NEDGE = 24576;
constexpr int NLAY  = 3;

__device__ __forceinline__ f32x4 mfma16(f16x8 a, f16x8 b, f32x4 c) {
    return __builtin_amdgcn_mfma_f32_16x16x32_f16(a, b, c, 0, 0, 0);
}

// ---------------- embeddings ----------------
__global__ void k_embed_nodes(const int* x, const float* atab, float* nodef, float* hiddenf) {
    const int v = blockIdx.x, h = threadIdx.x;  // TOTN x 128
    float s = 0.f;
    for (int c = 0; c < 9; ++c)
        s += atab[((size_t)(c * 119 + x[v * 9 + c])) * HD + h];
    nodef[(size_t)v * HD + h] = s;
    hiddenf[(size_t)v * HD + h] = 0.f;
}

// edge embeddings straight into f16 A-fragment layout
__global__ void k_embed_edges(const int* ea, const float* btab, f16* eftsA) {
    const int e = blockIdx.x, h = threadIdx.x;  // NEDGE x 128
    float s = 0.f;
    for (int c = 0; c < 3; ++c)
        s += btab[((size_t)(c * 6 + ea[e * 3 + c])) * HD + h];
    eftsA[(((size_t)(e >> 4) * 16 + (h >> 3)) * 16 + (e & 15)) * 8 + (h & 7)] = (f16)s;
}

__global__ void k_winit(int* winner) {
    winner[blockIdx.x * 256 + threadIdx.x] = -1;  // NG*NNODE*NNODE threads
}

// last-write-wins: largest edge id wins (numpy fancy-assignment semantics)
__global__ void k_winner(const int* esrc, const int* edst, int* winner) {
    const int e = blockIdx.x * 256 + threadIdx.x;  // NEDGE threads
    const int sg = esrc[e];
    const int g = sg / NNODE;
    const int li = sg - g * NNODE;
    const int lj = edst[e] - g * NNODE;
    atomicMax(&winner[((size_t)g * NNODE + li) * NNODE + lj], e);
}

// ------------- weight swizzle: Wmlp1/Wmlp2/Wme -> f16 B-fragment order -------------
__global__ void k_wswz(const float* W1, const float* W2, const float* We,
                       f16* o1, f16* o2, f16* oe) {
    const int idx = blockIdx.x * 256 + threadIdx.x;  // 6*128*128 threads
    const int mat = idx >> 14;
    const int r = idx & 16383;
    const int k = r >> 7, n = r & 127;
    const size_t dst = (size_t)mat * 16384 + (((k >> 3) * 128 + n) << 3) + (k & 7);
    o1[dst] = (f16)W1[idx];
    o2[dst] = (f16)W2[idx];
    oe[dst] = (f16)We[idx];
}

// ------- per-node GEMMs, 16-row-blocked f32: msg1'(+b_me+b_mg) / msg2 / o1 -------
__global__ __launch_bounds__(256) void k_ngemm(
    const float* nodef, const float* hiddenf,
    const float* Wm1, const float* Wm2, const float* Wo1,
    const float* bm1, const float* bm2, const float* bme,
    const float* bmg, const float* bo1,
    float* msg1, float* msg2, float* o1buf, int layer) {
    __shared__ float zl[16 * 256];  // 16 KB
    const int t0 = blockIdx.x;      // 0..95 (16-row tile)
    const int wh = blockIdx.y >> 1, s = blockIdx.y & 1, ls = layer * 2 + s;
    const int tid = threadIdx.x;
    for (int i = tid; i < 1024; i += 256) {
        const int row = i >> 6;
        const int c4 = i & 63;
        float4 v;
        if (c4 < 32) v = ((const float4*)(nodef + (size_t)(t0 * 16 + row) * HD))[c4];
        else         v = ((const float4*)(hiddenf + (size_t)(t0 * 16 + row) * HD))[c4 - 32];
        ((float4*)zl)[row * 64 + c4] = v;
    }
    __syncthreads();
    const int jl = tid >> 4;
    const int c0 = (tid & 15) * 8;
    const float* W;
    float* out;
    float acc[8];
    if (wh == 0) {
        W = Wm1 + (size_t)ls * 256 * HD;
        out = msg1 + (size_t)s * TOTN * HD;
        for (int u = 0; u < 8; ++u)
            acc[u] = bm1[ls * HD + c0 + u] + bme[ls * HD + c0 + u] + bmg[ls * HD + c0 + u];
    } else if (wh == 1) {
        W = Wm2 + (size_t)ls * 256 * HD;
        out = msg2 + (size_t)s * TOTN * HD;
        for (int u = 0; u < 8; ++u) acc[u] = bm2[ls * HD + c0 + u];
    } else {
        W = Wo1 + (size_t)ls * 256 * HD;
        out = o1buf + (size_t)s * TOTN * HD;
        for (int u = 0; u < 8; ++u) acc[u] = bo1[ls * HD + c0 + u];
    }
    for (int k = 0; k < 256; ++k) {
        const float zk = zl[jl * 256 + k];
        const float4 wa = *(const float4*)&W[(size_t)k * HD + c0];
        const float4 wb = *(const float4*)&W[(size_t)k * HD + c0 + 4];
        acc[0] += zk * wa.x; acc[1] += zk * wa.y;
        acc[2] += zk * wa.z; acc[3] += zk * wa.w;
        acc[4] += zk * wb.x; acc[5] += zk * wb.y;
        acc[6] += zk * wb.z; acc[7] += zk * wb.w;
    }
    float* op = out + (size_t)(t0 * 16 + jl) * HD + c0;
    *(float4*)op = make_float4(acc[0], acc[1], acc[2], acc[3]);
    *(float4*)(op + 4) = make_float4(acc[4], acc[5], acc[6], acc[7]);
}

// ------- per-edge GEMM (ALL 6 layer-stream mats at once): emsg = eftsA @ Wme -------
// grid (192, 6); 256 thr; block = 128 edges x 128 cols, K=128.
__global__ __launch_bounds__(256) void k_egemm(
    const f16* __restrict__ eftsA, const f16* __restrict__ omes,
    f16* __restrict__ emsg) {
    const int tid = threadIdx.x, lane = tid & 63, w = tid >> 6;
    const int mr = lane & 15, q = lane >> 4;
    const int ls = blockIdx.y;
    const f16* B = omes + (size_t)ls * 16384;
    f32x4 acc[2][8];
#pragma unroll
    for (int mt = 0; mt < 2; ++mt)
#pragma unroll
        for (int nt = 0; nt < 8; ++nt) acc[mt][nt] = (f32x4){0.f, 0.f, 0.f, 0.f};
#pragma unroll
    for (int kt = 0; kt < 4; ++kt) {
        const int kq = kt * 4 + q;
        f16x8 a0 = *(const f16x8*)&eftsA[(((size_t)(blockIdx.x * 8 + 2 * w + 0) * 16 + kq) * 16 + mr) * 8];
        f16x8 a1 = *(const f16x8*)&eftsA[(((size_t)(blockIdx.x * 8 + 2 * w + 1) * 16 + kq) * 16 + mr) * 8];
        const f16* bp = B + ((size_t)kq * HD) * 8;
#pragma unroll
        for (int nt = 0; nt < 8; ++nt) {
            f16x8 bv = *(const f16x8*)(bp + (nt * 16 + mr) * 8);
            acc[0][nt] = mfma16(a0, bv, acc[0][nt]);
            acc[1][nt] = mfma16(a1, bv, acc[1][nt]);
        }
    }
#pragma unroll
    for (int mt = 0; mt < 2; ++mt) {
        const int ebase = blockIdx.x * 128 + (2 * w + mt) * 16 + q * 4;
#pragma unroll
        for (int nt = 0; nt < 8; ++nt) {
            const int col = nt * 16 + mr;
#pragma unroll
            for (int r = 0; r < 4; ++r)
                emsg[((size_t)ls * NEDGE + ebase + r) * HD + col] = (f16)acc[mt][nt][r];
        }
    }
}

// ---------- fused pair MLP (f16 MFMA), one 8-i octet per block ----------
// grid (6 jt, NG, 24 zz = chunk*2+s, chunk 0..11); 256 thr; single 32KB LDS.
__global__ __launch_bounds__(256) void k_pairs(
    const float* __restrict__ msg1, const float* __restrict__ msg2,
    const f16* __restrict__ emsg, const int* __restrict__ winner,
    const f16* __restrict__ w1s, const float* __restrict__ bmlp1,
    const f16* __restrict__ w2s, const float* __restrict__ bmlp2,
    float* __restrict__ maxpart, int layer) {
    __shared__ __align__(16) f16 buf[128 * 128];  // 32 KB, time-shared P/Q/reduce
    const int tid = threadIdx.x, lane = tid & 63, w = tid >> 6;
    const int mr = lane & 15, q = lane >> 4;
    const int jt = blockIdx.x, b = blockIdx.y, zz = blockIdx.z;
    const int chunk = zz >> 1, s = zz & 1, ls = layer * 2 + s;
    const int j0 = jt * 16, i0 = chunk * 8;
    const float* M1 = msg1 + ((size_t)s * TOTN + b * NNODE) * HD;
    const float* M2 = msg2 + ((size_t)s * TOTN + b * NNODE) * HD;
    const f16* EM = emsg + (size_t)ls * NEDGE * HD;
    const f16* W1 = w1s + (size_t)ls * HD * HD;
    const f16* W2 = w2s + (size_t)ls * HD * HD;
    float b1c[8], b2c[8];
#pragma unroll
    for (int nt = 0; nt < 8; ++nt) {
        b1c[nt] = bmlp1[ls * HD + nt * 16 + mr];
        b2c[nt] = bmlp2[ls * HD + nt * 16 + mr];
    }
    // ---- build P = relu(msg1[j] + msg2[i] + edge) into A-frag layout ----
    {
        const int prow = tid >> 1, half = tid & 1;
        const int pj = prow & 15, pii = prow >> 4;
        const int i = i0 + pii;
        const int wv = winner[((size_t)b * NNODE + i) * NNODE + (j0 + pj)];
        const float* m1r = M1 + (size_t)(j0 + pj) * HD + half * 64;
        const float* m2r = M2 + (size_t)i * HD + half * 64;
        const f16* er = EM + (size_t)(wv < 0 ? 0 : wv) * HD + half * 64;
#pragma unroll
        for (int c8 = 0; c8 < 64; c8 += 8) {
            float4 x0 = *(const float4*)(m1r + c8);
            float4 x1 = *(const float4*)(m1r + c8 + 4);
            float4 y0 = *(const float4*)(m2r + c8);
            float4 y1 = *(const float4*)(m2r + c8 + 4);
            float v[8] = {x0.x + y0.x, x0.y + y0.y, x0.z + y0.z, x0.w + y0.w,
                          x1.x + y1.x, x1.y + y1.y, x1.z + y1.z, x1.w + y1.w};
            if (wv >= 0) {
                f16x8 e8 = *(const f16x8*)(er + c8);
#pragma unroll
                for (int u = 0; u < 8; ++u) v[u] += (float)e8[u];
            }
            f16x8 pv;
#pragma unroll
            for (int u = 0; u < 8; ++u) pv[u] = (f16)fmaxf(v[u], 0.f);
            const int k = half * 64 + c8;
            *(f16x8*)&buf[((pii * 16 + (k >> 3)) * 16 + pj) * 8] = pv;
        }
    }
    __syncthreads();
    // ---- GEMM1 ----
    f32x4 acc[2][8];
#pragma unroll
    for (int mt = 0; mt < 2; ++mt)
#pragma unroll
        for (int nt = 0; nt < 8; ++nt) acc[mt][nt] = (f32x4){0.f, 0.f, 0.f, 0.f};
#pragma unroll
    for (int kt = 0; kt < 4; ++kt) {
        f16x8 a0 = *(const f16x8*)&buf[(((2 * w + 0) * 16 + kt * 4 + q) * 16 + mr) * 8];
        f16x8 a1 = *(const f16x8*)&buf[(((2 * w + 1) * 16 + kt * 4 + q) * 16 + mr) * 8];
        const f16* bp = W1 + ((size_t)(kt * 4 + q) * HD) * 8;
#pragma unroll
        for (int nt = 0; nt < 8; ++nt) {
            f16x8 bv = *(const f16x8*)(bp + (nt * 16 + mr) * 8);
            acc[0][nt] = mfma16(a0, bv, acc[0][nt]);
            acc[1][nt] = mfma16(a1, bv, acc[1][nt]);
        }
    }
    __syncthreads();  // all P reads complete before buffer reuse
    // ---- write Q = relu(GEMM1 + b1) into same buffer (A-frag layout) ----
#pragma unroll
    for (int mt = 0; mt < 2; ++mt)
#pragma unroll
        for (int nt = 0; nt < 8; ++nt) {
            const int ng = nt * 2 + (mr >> 3), nj = mr & 7;
#pragma unroll
            for (int r = 0; r < 4; ++r) {
                float v = fmaxf(acc[mt][nt][r] + b1c[nt], 0.f);
                buf[(((2 * w + mt) * 16 + ng) * 16 + q * 4 + r) * 8 + nj] = (f16)v;
            }
        }
    __syncthreads();
    // ---- GEMM2 ----
#pragma unroll
    for (int mt = 0; mt < 2; ++mt)
#pragma unroll
        for (int nt = 0; nt < 8; ++nt) acc[mt][nt] = (f32x4){0.f, 0.f, 0.f, 0.f};
#pragma unroll
    for (int kt = 0; kt < 4; ++kt) {
        f16x8 a0 = *(const f16x8*)&buf[(((2 * w + 0) * 16 + kt * 4 + q) * 16 + mr) * 8];
        f16x8 a1 = *(const f16x8*)&buf[(((2 * w + 1) * 16 + kt * 4 + q) * 16 + mr) * 8];
        const f16* bp = W2 + ((size_t)(kt * 4 + q) * HD) * 8;
#pragma unroll
        for (int nt = 0; nt < 8; ++nt) {
            f16x8 bv = *(const f16x8*)(bp + (nt * 16 + mr) * 8);
            acc[0][nt] = mfma16(a0, bv, acc[0][nt]);
            acc[1][nt] = mfma16(a1, bv, acc[1][nt]);
        }
    }
    __syncthreads();  // all Q reads complete before reduce reuse
    // ---- cross-wave max over 8 i (2 per wave in-reg, 4 waves via LDS) ----
    float* red = (float*)buf;
#pragma unroll
    for (int nt = 0; nt < 8; ++nt)
#pragma unroll
        for (int r = 0; r < 4; ++r)
            red[(w * 16 + q * 4 + r) * 128 + nt * 16 + mr] =
                fmaxf(acc[0][nt][r], acc[1][nt][r]) + b2c[nt];
    __syncthreads();
    for (int t = tid; t < 16 * 128; t += 256) {
        float m0 = fmaxf(fmaxf(red[t], red[2048 + t]), fmaxf(red[4096 + t], red[6144 + t]));
        const int jj = t >> 7, col = t & 127;
        maxpart[((size_t)zz * TOTN + b * NNODE + j0 + jj) * HD + col] = m0;
    }
}

// -------- fused: ret = LN(relu(o1 + maxmsg@W_o2 + b_o2)); hidden = cat@W_red --------
// grid (TOTN); 256 thr = 2 stream-halves x 128 cols.
__global__ __launch_bounds__(256) void k_pr(
    const float* maxpart, const float* o1buf,
    const float* Wo2, const float* bo2, const float* lng, const float* lnb,
    const float* Wred, const float* bred, float* hiddenf, int layer) {
    __shared__ float al[256];
    __shared__ float r1[256];
    __shared__ float r2[256];
    __shared__ float ln[256];
    __shared__ float pp[256];
    const int row = blockIdx.x, tid = threadIdx.x;
    const int s = tid >> 7, c = tid & 127, ls = layer * 2 + s;
    float m = -3.402823466e38f;
#pragma unroll
    for (int ch = 0; ch < 12; ++ch)
        m = fmaxf(m, maxpart[((size_t)(ch * 2 + s) * TOTN + row) * HD + c]);
    al[tid] = m;
    __syncthreads();
    const float* W = Wo2 + (size_t)ls * HD * HD;
    float acc = bo2[ls * HD + c];
    for (int k = 0; k < HD; ++k)
        acc += al[s * 128 + k] * W[(size_t)k * HD + c];
    const float v = fmaxf(acc + o1buf[((size_t)s * TOTN + row) * HD + c], 0.f);
    r1[tid] = v;
    r2[tid] = v * v;
    __syncthreads();
    for (int off = 64; off > 0; off >>= 1) {
        if (c < off) {
            r1[tid] += r1[tid + off];
            r2[tid] += r2[tid + off];
        }
        __syncthreads();
    }
    const float mean = r1[s * 128] * (1.f / 128.f);
    float var = r2[s * 128] * (1.f / 128.f) - mean * mean;
    var = fmaxf(var, 0.f);
    const float rstd = 1.f / sqrtf(var + 1e-5f);
    ln[tid] = (v - mean) * rstd * lng[ls * HD + c] + lnb[ls * HD + c];
    __syncthreads();
    // hidden[row][c] = bred + sum_{k=0..255} ln[k]*Wred[k][c]; k split across halves
    const float* Wr = Wred + (size_t)layer * 256 * HD;
    float a2 = 0.f;
    for (int k = 0; k < 128; ++k)
        a2 += ln[s * 128 + k] * Wr[(size_t)(s * 128 + k) * HD + c];
    pp[tid] = a2;
    __syncthreads();
    if (tid < 128)
        hiddenf[(size_t)row * HD + tid] = pp[tid] + pp[128 + tid] + bred[layer * HD + tid];
}

// ---------------- mean-pool + 2-layer head; float32 output ----------------
__global__ void k_final(const float* hiddenf, const float* Wp1, const float* bp1,
                        const float* Wp2, const float* bp2, float* out) {
    __shared__ float se[128];
    __shared__ float sr[128];
    const int b = blockIdx.x, h = threadIdx.x;
    float acc = 0.f;
    for (int v = 0; v < NNODE; ++v)
        acc += hiddenf[((size_t)b * NNODE + v) * HD + h];
    se[h] = acc * (1.f / 96.f);
    __syncthreads();
    float a2 = bp1[h];
    for (int k = 0; k < 128; ++k)
        a2 += se[k] * Wp1[(size_t)k * HD + h];
    a2 = fmaxf(a2, 0.f);
    sr[h] = a2 * Wp2[h];
    __syncthreads();
    for (int off = 64; off > 0; off >>= 1) {
        if (h < off) sr[h] += sr[h + off];
        __syncthreads();
    }
    if (h == 0) out[b] = sr[0] + bp2[0];
}

extern "C" void kernel_launch(void* const* d_in, const int* in_sizes, int n_in,
                              void* d_out, int out_size, void* d_ws, size_t ws_size,
                              hipStream_t stream) {
    (void)in_sizes; (void)n_in; (void)out_size; (void)ws_size;
    const int* x    = (const int*)d_in[0];
    const int* ea   = (const int*)d_in[1];
    const int* esrc = (const int*)d_in[2];
    const int* edst = (const int*)d_in[3];
    const float* atab = (const float*)d_in[6];
    const float* btab = (const float*)d_in[7];
    const float* Wm1 = (const float*)d_in[8];    const float* bm1 = (const float*)d_in[9];
    const float* Wm2 = (const float*)d_in[10];   const float* bm2 = (const float*)d_in[11];
    const float* Wme = (const float*)d_in[12];   const float* bme = (const float*)d_in[13];
    const float* bmg = (const float*)d_in[15];
    const float* Wmlp1 = (const float*)d_in[16]; const float* bmlp1 = (const float*)d_in[17];
    const float* Wmlp2 = (const float*)d_in[18]; const float* bmlp2 = (const float*)d_in[19];
    const float* Wo1 = (const float*)d_in[20];   const float* bo1 = (const float*)d_in[21];
    const float* Wo2 = (const float*)d_in[22];   const float* bo2 = (const float*)d_in[23];
    const float* lng = (const float*)d_in[24];   const float* lnb = (const float*)d_in[25];
    const float* Wred = (const float*)d_in[26];  const float* bred = (const float*)d_in[27];
    const float* Wp1 = (const float*)d_in[28];   const float* bp1 = (const float*)d_in[29];
    const float* Wp2 = (const float*)d_in[30];   const float* bp2 = (const float*)d_in[31];

    char* cur = (char*)d_ws;
    float* nodef = (float*)cur;   cur += (size_t)TOTN * HD * 4;
    float* hiddenf = (float*)cur; cur += (size_t)TOTN * HD * 4;
    f16* eftsA = (f16*)cur;       cur += (size_t)NEDGE * HD * 2;
    f16* emsg = (f16*)cur;        cur += (size_t)6 * NEDGE * HD * 2;
    float* msg1 = (float*)cur;    cur += (size_t)2 * TOTN * HD * 4;
    float* msg2 = (float*)cur;    cur += (size_t)2 * TOTN * HD * 4;
    float* o1buf = (float*)cur;   cur += (size_t)2 * TOTN * HD * 4;
    float* maxpart = (float*)cur; cur += (size_t)24 * TOTN * HD * 4;
    int* winner = (int*)cur;      cur += (size_t)NG * NNODE * NNODE * 4;
    f16* w1s = (f16*)cur;         cur += (size_t)6 * HD * HD * 2;
    f16* w2s = (f16*)cur;         cur += (size_t)6 * HD * HD * 2;
    f16* omes = (f16*)cur;        cur += (size_t)6 * HD * HD * 2;

    k_winit<<<(NG * NNODE * NNODE) / 256, 256, 0, stream>>>(winner);
    k_embed_nodes<<<TOTN, 128, 0, stream>>>(x, atab, nodef, hiddenf);
    k_embed_edges<<<NEDGE, 128, 0, stream>>>(ea, btab, eftsA);
    k_winner<<<NEDGE / 256, 256, 0, stream>>>(esrc, edst, winner);
    k_wswz<<<(6 * HD * HD) / 256, 256, 0, stream>>>(Wmlp1, Wmlp2, Wme, w1s, w2s, omes);
    k_egemm<<<dim3(192, 6), 256, 0, stream>>>(eftsA, omes, emsg);
    for (int layer = 0; layer < NLAY; ++layer) {
        k_ngemm<<<dim3(96, 6), 256, 0, stream>>>(nodef, hiddenf, Wm1, Wm2, Wo1,
                                                 bm1, bm2, bme, bmg, bo1,
                                                 msg1, msg2, o1buf, layer);
        k_pairs<<<dim3(6, NG, 24), 256, 0, stream>>>(msg1, msg2, emsg, winner,
                                                     w1s, bmlp1, w2s, bmlp2,
                                                     maxpart, layer);
        k_pr<<<TOTN, 256, 0, stream>>>(maxpart, o1buf, Wo2, bo2, lng, lnb,
                                       Wred, bred, hiddenf, layer);
    }
    k_final<<<NG, 128, 0, stream>>>(hiddenf, Wp1, bp1, Wp2, bp2, (float*)d_out);
}

// Round 12
// 556.879 us; speedup vs baseline: 8.9737x; 1.0067x over previous
//
#include <hip/hip_runtime.h>
#include <cstddef>

typedef _Float16 f16;
typedef f16 f16x8 __attribute__((ext_vector_type(8)));
typedef float f32x4 __attribute__((ext_vector_type(4)));

constexpr int NG    = 16;    // graphs
constexpr int NNODE = 96;    // nodes per graph
constexpr int TOTN  = 1536;  // NG*NNODE
constexpr int HD    = 128;   // hidden
constexpr int NEDGE = 24576;
constexpr int NLAY  = 3;

__device__ __forceinline__ f32x4 mfma16(f16x8 a, f16x8 b, f32x4 c) {
    return __builtin_amdgcn_mfma_f32_16x16x32_f16(a, b, c, 0, 0, 0);
}

// ---------------- embeddings ----------------
__global__ void k_embed_nodes(const int* x, const float* atab, float* nodef, float* hiddenf) {
    const int v = blockIdx.x, h = threadIdx.x;  // TOTN x 128
    float s = 0.f;
    for (int c = 0; c < 9; ++c)
        s += atab[((size_t)(c * 119 + x[v * 9 + c])) * HD + h];
    nodef[(size_t)v * HD + h] = s;
    hiddenf[(size_t)v * HD + h] = 0.f;
}

__global__ void k_embed_edges(const int* ea, const float* btab, f16* eftsA) {
    const int e = blockIdx.x, h = threadIdx.x;  // NEDGE x 128
    float s = 0.f;
    for (int c = 0; c < 3; ++c)
        s += btab[((size_t)(c * 6 + ea[e * 3 + c])) * HD + h];
    eftsA[(((size_t)(e >> 4) * 16 + (h >> 3)) * 16 + (e & 15)) * 8 + (h & 7)] = (f16)s;
}

__global__ void k_winit(int* winner) {
    winner[blockIdx.x * 256 + threadIdx.x] = -1;  // NG*NNODE*NNODE threads
}

__global__ void k_winner(const int* esrc, const int* edst, int* winner) {
    const int e = blockIdx.x * 256 + threadIdx.x;  // NEDGE threads
    const int sg = esrc[e];
    const int g = sg / NNODE;
    const int li = sg - g * NNODE;
    const int lj = edst[e] - g * NNODE;
    atomicMax(&winner[((size_t)g * NNODE + li) * NNODE + lj], e);
}

// ------- weight swizzle: ALL weights -> f16 B-fragment order -------
// dst[mat][ ((k>>3)*128 + n)*8 + (k&7) ] = (f16) src[mat][k*128+n]
__global__ void k_wswz(const float* Wm1, const float* Wm2, const float* Wo1,
                       const float* Wred, const float* Wo2, const float* W1,
                       const float* W2, const float* We,
                       f16* sm1, f16* sm2, f16* so1, f16* sred, f16* so2,
                       f16* s1, f16* s2, f16* sme) {
    const int idx = blockIdx.x * 256 + threadIdx.x;  // 1081344 threads
    const int S256 = 6 * 256 * 128;   // 196608
    const int SRED = 3 * 256 * 128;   // 98304
    const int S128 = 6 * 128 * 128;   // 98304
    const float* src;
    f16* dst;
    int rel, sh;
    if (idx < S256)                   { src = Wm1;  dst = sm1;  rel = idx;              sh = 15; }
    else if (idx < 2 * S256)          { src = Wm2;  dst = sm2;  rel = idx - S256;       sh = 15; }
    else if (idx < 3 * S256)          { src = Wo1;  dst = so1;  rel = idx - 2 * S256;   sh = 15; }
    else if (idx < 3 * S256 + SRED)   { src = Wred; dst = sred; rel = idx - 3 * S256;   sh = 15; }
    else if (idx < 3 * S256 + SRED + S128)
        { src = Wo2; dst = so2; rel = idx - 3 * S256 - SRED; sh = 14; }
    else if (idx < 3 * S256 + SRED + 2 * S128)
        { src = W1;  dst = s1;  rel = idx - 3 * S256 - SRED - S128; sh = 14; }
    else if (idx < 3 * S256 + SRED + 3 * S128)
        { src = W2;  dst = s2;  rel = idx - 3 * S256 - SRED - 2 * S128; sh = 14; }
    else if (idx < 3 * S256 + SRED + 4 * S128)
        { src = We;  dst = sme; rel = idx - 3 * S256 - SRED - 3 * S128; sh = 14; }
    else return;
    const int mat = rel >> sh;
    const int r2 = rel & ((1 << sh) - 1);
    const int k = r2 >> 7, n = r2 & 127;
    dst[(size_t)mat * (1 << sh) + (((k >> 3) * 128 + n) << 3) + (k & 7)] = (f16)src[rel];
}

// ------- per-node GEMMs via MFMA: msg1'(+b_me+b_mg) / msg2 / o1 -------
// grid (12, 6): x = 128-row tile, y = wh*2+s. K=256 from [nodef|hiddenf].
__global__ __launch_bounds__(256) void k_ngemm(
    const float* __restrict__ nodef, const float* __restrict__ hiddenf,
    const f16* __restrict__ sm1, const f16* __restrict__ sm2, const f16* __restrict__ so1,
    const float* __restrict__ bm1, const float* __restrict__ bm2,
    const float* __restrict__ bme, const float* __restrict__ bmg,
    const float* __restrict__ bo1,
    float* __restrict__ msg1, float* __restrict__ msg2, float* __restrict__ o1buf,
    int layer) {
    const int tid = threadIdx.x, lane = tid & 63, w = tid >> 6;
    const int mr = lane & 15, q = lane >> 4;
    const int rbase = blockIdx.x * 128;
    const int wh = blockIdx.y >> 1, s = blockIdx.y & 1, ls = layer * 2 + s;
    const f16* B;
    float* out;
    float bias[8];
    if (wh == 0) {
        B = sm1 + (size_t)ls * 32768; out = msg1 + (size_t)s * TOTN * HD;
        for (int nt = 0; nt < 8; ++nt) {
            const int col = nt * 16 + mr;
            bias[nt] = bm1[ls * HD + col] + bme[ls * HD + col] + bmg[ls * HD + col];
        }
    } else if (wh == 1) {
        B = sm2 + (size_t)ls * 32768; out = msg2 + (size_t)s * TOTN * HD;
        for (int nt = 0; nt < 8; ++nt) bias[nt] = bm2[ls * HD + nt * 16 + mr];
    } else {
        B = so1 + (size_t)ls * 32768; out = o1buf + (size_t)s * TOTN * HD;
        for (int nt = 0; nt < 8; ++nt) bias[nt] = bo1[ls * HD + nt * 16 + mr];
    }
    f32x4 acc[2][8];
#pragma unroll
    for (int mt = 0; mt < 2; ++mt)
#pragma unroll
        for (int nt = 0; nt < 8; ++nt) acc[mt][nt] = (f32x4){0.f, 0.f, 0.f, 0.f};
#pragma unroll
    for (int kt = 0; kt < 8; ++kt) {
        const int k0 = kt * 32 + q * 8;
        const float* zsrc = (k0 < 128) ? nodef : hiddenf;
        const int koff = k0 & 127;
        f16x8 a[2];
#pragma unroll
        for (int mt = 0; mt < 2; ++mt) {
            const int row = rbase + (2 * w + mt) * 16 + mr;
            float4 p0 = *(const float4*)(zsrc + (size_t)row * HD + koff);
            float4 p1 = *(const float4*)(zsrc + (size_t)row * HD + koff + 4);
            a[mt][0] = (f16)p0.x; a[mt][1] = (f16)p0.y; a[mt][2] = (f16)p0.z; a[mt][3] = (f16)p0.w;
            a[mt][4] = (f16)p1.x; a[mt][5] = (f16)p1.y; a[mt][6] = (f16)p1.z; a[mt][7] = (f16)p1.w;
        }
        const f16* bp = B + ((size_t)(kt * 4 + q) * HD) * 8;
#pragma unroll
        for (int nt = 0; nt < 8; ++nt) {
            f16x8 bv = *(const f16x8*)(bp + (nt * 16 + mr) * 8);
            acc[0][nt] = mfma16(a[0], bv, acc[0][nt]);
            acc[1][nt] = mfma16(a[1], bv, acc[1][nt]);
        }
    }
#pragma unroll
    for (int mt = 0; mt < 2; ++mt)
#pragma unroll
        for (int nt = 0; nt < 8; ++nt) {
            const int col = nt * 16 + mr;
#pragma unroll
            for (int r = 0; r < 4; ++r) {
                const int row = rbase + (2 * w + mt) * 16 + q * 4 + r;
                out[(size_t)row * HD + col] = acc[mt][nt][r] + bias[nt];
            }
        }
}

// ------- per-edge GEMM (ALL 6 mats): emsg = eftsA @ Wme -------
__global__ __launch_bounds__(256) void k_egemm(
    const f16* __restrict__ eftsA, const f16* __restrict__ sme,
    f16* __restrict__ emsg) {
    const int tid = threadIdx.x, lane = tid & 63, w = tid >> 6;
    const int mr = lane & 15, q = lane >> 4;
    const int ls = blockIdx.y;
    const f16* B = sme + (size_t)ls * 16384;
    f32x4 acc[2][8];
#pragma unroll
    for (int mt = 0; mt < 2; ++mt)
#pragma unroll
        for (int nt = 0; nt < 8; ++nt) acc[mt][nt] = (f32x4){0.f, 0.f, 0.f, 0.f};
#pragma unroll
    for (int kt = 0; kt < 4; ++kt) {
        const int kq = kt * 4 + q;
        f16x8 a0 = *(const f16x8*)&eftsA[(((size_t)(blockIdx.x * 8 + 2 * w + 0) * 16 + kq) * 16 + mr) * 8];
        f16x8 a1 = *(const f16x8*)&eftsA[(((size_t)(blockIdx.x * 8 + 2 * w + 1) * 16 + kq) * 16 + mr) * 8];
        const f16* bp = B + ((size_t)kq * HD) * 8;
#pragma unroll
        for (int nt = 0; nt < 8; ++nt) {
            f16x8 bv = *(const f16x8*)(bp + (nt * 16 + mr) * 8);
            acc[0][nt] = mfma16(a0, bv, acc[0][nt]);
            acc[1][nt] = mfma16(a1, bv, acc[1][nt]);
        }
    }
#pragma unroll
    for (int mt = 0; mt < 2; ++mt) {
        const int ebase = blockIdx.x * 128 + (2 * w + mt) * 16 + q * 4;
#pragma unroll
        for (int nt = 0; nt < 8; ++nt) {
            const int col = nt * 16 + mr;
#pragma unroll
            for (int r = 0; r < 4; ++r)
                emsg[((size_t)ls * NEDGE + ebase + r) * HD + col] = (f16)acc[mt][nt][r];
        }
    }
}

// ---------- fused pair MLP (f16 MFMA), one 8-i octet per block (unchanged) ----------
__global__ __launch_bounds__(256) void k_pairs(
    const float* __restrict__ msg1, const float* __restrict__ msg2,
    const f16* __restrict__ emsg, const int* __restrict__ winner,
    const f16* __restrict__ w1s, const float* __restrict__ bmlp1,
    const f16* __restrict__ w2s, const float* __restrict__ bmlp2,
    float* __restrict__ maxpart, int layer) {
    __shared__ __align__(16) f16 buf[128 * 128];  // 32 KB, time-shared
    const int tid = threadIdx.x, lane = tid & 63, w = tid >> 6;
    const int mr = lane & 15, q = lane >> 4;
    const int jt = blockIdx.x, b = blockIdx.y, zz = blockIdx.z;
    const int chunk = zz >> 1, s = zz & 1, ls = layer * 2 + s;
    const int j0 = jt * 16, i0 = chunk * 8;
    const float* M1 = msg1 + ((size_t)s * TOTN + b * NNODE) * HD;
    const float* M2 = msg2 + ((size_t)s * TOTN + b * NNODE) * HD;
    const f16* EM = emsg + (size_t)ls * NEDGE * HD;
    const f16* W1 = w1s + (size_t)ls * HD * HD;
    const f16* W2 = w2s + (size_t)ls * HD * HD;
    float b1c[8], b2c[8];
#pragma unroll
    for (int nt = 0; nt < 8; ++nt) {
        b1c[nt] = bmlp1[ls * HD + nt * 16 + mr];
        b2c[nt] = bmlp2[ls * HD + nt * 16 + mr];
    }
    {
        const int prow = tid >> 1, half = tid & 1;
        const int pj = prow & 15, pii = prow >> 4;
        const int i = i0 + pii;
        const int wv = winner[((size_t)b * NNODE + i) * NNODE + (j0 + pj)];
        const float* m1r = M1 + (size_t)(j0 + pj) * HD + half * 64;
        const float* m2r = M2 + (size_t)i * HD + half * 64;
        const f16* er = EM + (size_t)(wv < 0 ? 0 : wv) * HD + half * 64;
#pragma unroll
        for (int c8 = 0; c8 < 64; c8 += 8) {
            float4 x0 = *(const float4*)(m1r + c8);
            float4 x1 = *(const float4*)(m1r + c8 + 4);
            float4 y0 = *(const float4*)(m2r + c8);
            float4 y1 = *(const float4*)(m2r + c8 + 4);
            float v[8] = {x0.x + y0.x, x0.y + y0.y, x0.z + y0.z, x0.w + y0.w,
                          x1.x + y1.x, x1.y + y1.y, x1.z + y1.z, x1.w + y1.w};
            if (wv >= 0) {
                f16x8 e8 = *(const f16x8*)(er + c8);
#pragma unroll
                for (int u = 0; u < 8; ++u) v[u] += (float)e8[u];
            }
            f16x8 pv;
#pragma unroll
            for (int u = 0; u < 8; ++u) pv[u] = (f16)fmaxf(v[u], 0.f);
            const int k = half * 64 + c8;
            *(f16x8*)&buf[((pii * 16 + (k >> 3)) * 16 + pj) * 8] = pv;
        }
    }
    __syncthreads();
    f32x4 acc[2][8];
#pragma unroll
    for (int mt = 0; mt < 2; ++mt)
#pragma unroll
        for (int nt = 0; nt < 8; ++nt) acc[mt][nt] = (f32x4){0.f, 0.f, 0.f, 0.f};
#pragma unroll
    for (int kt = 0; kt < 4; ++kt) {
        f16x8 a0 = *(const f16x8*)&buf[(((2 * w + 0) * 16 + kt * 4 + q) * 16 + mr) * 8];
        f16x8 a1 = *(const f16x8*)&buf[(((2 * w + 1) * 16 + kt * 4 + q) * 16 + mr) * 8];
        const f16* bp = W1 + ((size_t)(kt * 4 + q) * HD) * 8;
#pragma unroll
        for (int nt = 0; nt < 8; ++nt) {
            f16x8 bv = *(const f16x8*)(bp + (nt * 16 + mr) * 8);
            acc[0][nt] = mfma16(a0, bv, acc[0][nt]);
            acc[1][nt] = mfma16(a1, bv, acc[1][nt]);
        }
    }
    __syncthreads();
#pragma unroll
    for (int mt = 0; mt < 2; ++mt)
#pragma unroll
        for (int nt = 0; nt < 8; ++nt) {
            const int ng = nt * 2 + (mr >> 3), nj = mr & 7;
#pragma unroll
            for (int r = 0; r < 4; ++r) {
                float v = fmaxf(acc[mt][nt][r] + b1c[nt], 0.f);
                buf[(((2 * w + mt) * 16 + ng) * 16 + q * 4 + r) * 8 + nj] = (f16)v;
            }
        }
    __syncthreads();
#pragma unroll
    for (int mt = 0; mt < 2; ++mt)
#pragma unroll
        for (int nt = 0; nt < 8; ++nt) acc[mt][nt] = (f32x4){0.f, 0.f, 0.f, 0.f};
#pragma unroll
    for (int kt = 0; kt < 4; ++kt) {
        f16x8 a0 = *(const f16x8*)&buf[(((2 * w + 0) * 16 + kt * 4 + q) * 16 + mr) * 8];
        f16x8 a1 = *(const f16x8*)&buf[(((2 * w + 1) * 16 + kt * 4 + q) * 16 + mr) * 8];
        const f16* bp = W2 + ((size_t)(kt * 4 + q) * HD) * 8;
#pragma unroll
        for (int nt = 0; nt < 8; ++nt) {
            f16x8 bv = *(const f16x8*)(bp + (nt * 16 + mr) * 8);
            acc[0][nt] = mfma16(a0, bv, acc[0][nt]);
            acc[1][nt] = mfma16(a1, bv, acc[1][nt]);
        }
    }
    __syncthreads();
    float* red = (float*)buf;
#pragma unroll
    for (int nt = 0; nt < 8; ++nt)
#pragma unroll
        for (int r = 0; r < 4; ++r)
            red[(w * 16 + q * 4 + r) * 128 + nt * 16 + mr] =
                fmaxf(acc[0][nt][r], acc[1][nt][r]) + b2c[nt];
    __syncthreads();
    for (int t = tid; t < 16 * 128; t += 256) {
        float m0 = fmaxf(fmaxf(red[t], red[2048 + t]), fmaxf(red[4096 + t], red[6144 + t]));
        const int jj = t >> 7, col = t & 127;
        maxpart[((size_t)zz * TOTN + b * NNODE + j0 + jj) * HD + col] = m0;
    }
}

// ---- fused MFMA: maxreduce -> o2 GEMM -> LN -> red GEMM -> hidden ----
// grid (24); 256 thr; block = 64 node rows x 2 streams (m=128 for o2).
__global__ __launch_bounds__(256) void k_pr(
    const float* __restrict__ maxpart, const float* __restrict__ o1buf,
    const f16* __restrict__ so2, const float* __restrict__ bo2,
    const float* __restrict__ lng, const float* __restrict__ lnb,
    const f16* __restrict__ sred, const float* __restrict__ bred,
    float* __restrict__ hiddenf, int layer) {
    __shared__ __align__(16) f16 Af[16384];  // 32 KB, time-shared A1/A2
    const int tid = threadIdx.x, lane = tid & 63, w = tid >> 6;
    const int mr = lane & 15, q = lane >> 4;
    const int row0 = blockIdx.x * 64;
    // ---- build A1: max over 12 chunks, f16, layout [s*4+mt][kg16][row16][8] ----
    {
        const int mrow = tid >> 1, half = tid & 1;
        const int sb = mrow >> 6, rl = mrow & 63;
        const int row = row0 + rl;
#pragma unroll
        for (int c8 = 0; c8 < 64; c8 += 8) {
            const int col = half * 64 + c8;
            float mx[8] = {-3.4e38f, -3.4e38f, -3.4e38f, -3.4e38f,
                           -3.4e38f, -3.4e38f, -3.4e38f, -3.4e38f};
#pragma unroll
            for (int ch = 0; ch < 12; ++ch) {
                const float* p = maxpart + ((size_t)(ch * 2 + sb) * TOTN + row) * HD + col;
                float4 u0 = *(const float4*)p;
                float4 u1 = *(const float4*)(p + 4);
                mx[0] = fmaxf(mx[0], u0.x); mx[1] = fmaxf(mx[1], u0.y);
                mx[2] = fmaxf(mx[2], u0.z); mx[3] = fmaxf(mx[3], u0.w);
                mx[4] = fmaxf(mx[4], u1.x); mx[5] = fmaxf(mx[5], u1.y);
                mx[6] = fmaxf(mx[6], u1.z); mx[7] = fmaxf(mx[7], u1.w);
            }
            f16x8 pv;
#pragma unroll
            for (int u = 0; u < 8; ++u) pv[u] = (f16)mx[u];
            *(f16x8*)&Af[(((sb * 4 + (rl >> 4)) * 16 + (col >> 3)) * 16 + (rl & 15)) * 8] = pv;
        }
    }
    __syncthreads();
    // ---- o2 GEMM: waves 0-1 -> s0, 2-3 -> s1; each wave 2 m-tiles (32 rows) ----
    const int sw = w >> 1, ls = layer * 2 + sw;
    const f16* B1 = so2 + (size_t)ls * 16384;
    f32x4 acc[2][8];
#pragma unroll
    for (int mt = 0; mt < 2; ++mt)
#pragma unroll
        for (int nt = 0; nt < 8; ++nt) acc[mt][nt] = (f32x4){0.f, 0.f, 0.f, 0.f};
#pragma unroll
    for (int kt = 0; kt < 4; ++kt) {
        const int kq = kt * 4 + q;
        f16x8 a0 = *(const f16x8*)&Af[(((sw * 4 + (w & 1) * 2 + 0) * 16 + kq) * 16 + mr) * 8];
        f16x8 a1 = *(const f16x8*)&Af[(((sw * 4 + (w & 1) * 2 + 1) * 16 + kq) * 16 + mr) * 8];
        const f16* bp = B1 + ((size_t)kq * HD) * 8;
#pragma unroll
        for (int nt = 0; nt < 8; ++nt) {
            f16x8 bv = *(const f16x8*)(bp + (nt * 16 + mr) * 8);
            acc[0][nt] = mfma16(a0, bv, acc[0][nt]);
            acc[1][nt] = mfma16(a1, bv, acc[1][nt]);
        }
    }
    // ---- epilogue: + o1 + bo2, relu, LN (per-row stats via mr-lane shuffles) ----
    float lngv[8], lnbv[8], bo2v[8];
#pragma unroll
    for (int nt = 0; nt < 8; ++nt) {
        const int col = nt * 16 + mr;
        lngv[nt] = lng[ls * HD + col];
        lnbv[nt] = lnb[ls * HD + col];
        bo2v[nt] = bo2[ls * HD + col];
    }
#pragma unroll
    for (int mt = 0; mt < 2; ++mt) {
#pragma unroll
        for (int nt = 0; nt < 8; ++nt) {
            const int col = nt * 16 + mr;
#pragma unroll
            for (int r = 0; r < 4; ++r) {
                const int rl = (w & 1) * 32 + mt * 16 + q * 4 + r;
                float v = acc[mt][nt][r] + bo2v[nt] +
                          o1buf[((size_t)sw * TOTN + row0 + rl) * HD + col];
                acc[mt][nt][r] = fmaxf(v, 0.f);
            }
        }
#pragma unroll
        for (int r = 0; r < 4; ++r) {
            float su = 0.f, sq = 0.f;
#pragma unroll
            for (int nt = 0; nt < 8; ++nt) {
                su += acc[mt][nt][r];
                sq += acc[mt][nt][r] * acc[mt][nt][r];
            }
#pragma unroll
            for (int mask = 1; mask <= 8; mask <<= 1) {
                su += __shfl_xor(su, mask, 64);
                sq += __shfl_xor(sq, mask, 64);
            }
            const float mean = su * (1.f / 128.f);
            float var = sq * (1.f / 128.f) - mean * mean;
            var = fmaxf(var, 0.f);
            const float rstd = 1.f / sqrtf(var + 1e-5f);
#pragma unroll
            for (int nt = 0; nt < 8; ++nt)
                acc[mt][nt][r] = (acc[mt][nt][r] - mean) * rstd * lngv[nt] + lnbv[nt];
        }
    }
    __syncthreads();  // A1 reads done before overwrite
    // ---- write A2 (f16, [mt4][kg32][row16][8], k = s*128+col) ----
#pragma unroll
    for (int mt = 0; mt < 2; ++mt)
#pragma unroll
        for (int nt = 0; nt < 8; ++nt) {
            const int kg2 = sw * 16 + nt * 2 + (mr >> 3), j2 = mr & 7;
#pragma unroll
            for (int r = 0; r < 4; ++r) {
                const int rl = (w & 1) * 32 + mt * 16 + q * 4 + r;
                Af[(((rl >> 4) * 32 + kg2) * 16 + (rl & 15)) * 8 + j2] = (f16)acc[mt][nt][r];
            }
        }
    __syncthreads();
    // ---- red GEMM: wave w -> m-tile w (16 rows), K=256 ----
    const f16* B2 = sred + (size_t)layer * 32768;
    f32x4 a2[8];
#pragma unroll
    for (int nt = 0; nt < 8; ++nt) a2[nt] = (f32x4){0.f, 0.f, 0.f, 0.f};
#pragma unroll
    for (int kt = 0; kt < 8; ++kt) {
        const int kq = kt * 4 + q;
        f16x8 av = *(const f16x8*)&Af[((w * 32 + kq) * 16 + mr) * 8];
        const f16* bp = B2 + ((size_t)kq * HD) * 8;
#pragma unroll
        for (int nt = 0; nt < 8; ++nt) {
            f16x8 bv = *(const f16x8*)(bp + (nt * 16 + mr) * 8);
            a2[nt] = mfma16(av, bv, a2[nt]);
        }
    }
#pragma unroll
    for (int nt = 0; nt < 8; ++nt) {
        const int col = nt * 16 + mr;
        const float bb = bred[layer * HD + col];
#pragma unroll
        for (int r = 0; r < 4; ++r)
            hiddenf[(size_t)(row0 + w * 16 + q * 4 + r) * HD + col] = a2[nt][r] + bb;
    }
}

// ---------------- mean-pool + 2-layer head; float32 output ----------------
__global__ void k_final(const float* hiddenf, const float* Wp1, const float* bp1,
                        const float* Wp2, const float* bp2, float* out) {
    __shared__ float se[128];
    __shared__ float sr[128];
    const int b = blockIdx.x, h = threadIdx.x;
    float acc = 0.f;
    for (int v = 0; v < NNODE; ++v)
        acc += hiddenf[((size_t)b * NNODE + v) * HD + h];
    se[h] = acc * (1.f / 96.f);
    __syncthreads();
    float a2 = bp1[h];
    for (int k = 0; k < 128; ++k)
        a2 += se[k] * Wp1[(size_t)k * HD + h];
    a2 = fmaxf(a2, 0.f);
    sr[h] = a2 * Wp2[h];
    __syncthreads();
    for (int off = 64; off > 0; off >>= 1) {
        if (h < off) sr[h] += sr[h + off];
        __syncthreads();
    }
    if (h == 0) out[b] = sr[0] + bp2[0];
}

extern "C" void kernel_launch(void* const* d_in, const int* in_sizes, int n_in,
                              void* d_out, int out_size, void* d_ws, size_t ws_size,
                              hipStream_t stream) {
    (void)in_sizes; (void)n_in; (void)out_size; (void)ws_size;
    const int* x    = (const int*)d_in[0];
    const int* ea   = (const int*)d_in[1];
    const int* esrc = (const int*)d_in[2];
    const int* edst = (const int*)d_in[3];
    const float* atab = (const float*)d_in[6];
    const float* btab = (const float*)d_in[7];
    const float* Wm1 = (const float*)d_in[8];    const float* bm1 = (const float*)d_in[9];
    const float* Wm2 = (const float*)d_in[10];   const float* bm2 = (const float*)d_in[11];
    const float* Wme = (const float*)d_in[12];   const float* bme = (const float*)d_in[13];
    const float* bmg = (const float*)d_in[15];
    const float* Wmlp1 = (const float*)d_in[16]; const float* bmlp1 = (const float*)d_in[17];
    const float* Wmlp2 = (const float*)d_in[18]; const float* bmlp2 = (const float*)d_in[19];
    const float* Wo1 = (const float*)d_in[20];   const float* bo1 = (const float*)d_in[21];
    const float* Wo2 = (const float*)d_in[22];   const float* bo2 = (const float*)d_in[23];
    const float* lng = (const float*)d_in[24];   const float* lnb = (const float*)d_in[25];
    const float* Wred = (const float*)d_in[26];  const float* bred = (const float*)d_in[27];
    const float* Wp1 = (const float*)d_in[28];   const float* bp1 = (const float*)d_in[29];
    const float* Wp2 = (const float*)d_in[30];   const float* bp2 = (const float*)d_in[31];

    char* cur = (char*)d_ws;
    float* nodef = (float*)cur;   cur += (size_t)TOTN * HD * 4;
    float* hiddenf = (float*)cur; cur += (size_t)TOTN * HD * 4;
    f16* eftsA = (f16*)cur;       cur += (size_t)NEDGE * HD * 2;
    f16* emsg = (f16*)cur;        cur += (size_t)6 * NEDGE * HD * 2;
    float* msg1 = (float*)cur;    cur += (size_t)2 * TOTN * HD * 4;
    float* msg2 = (float*)cur;    cur += (size_t)2 * TOTN * HD * 4;
    float* o1buf = (float*)cur;   cur += (size_t)2 * TOTN * HD * 4;
    float* maxpart = (float*)cur; cur += (size_t)24 * TOTN * HD * 4;
    int* winner = (int*)cur;      cur += (size_t)NG * NNODE * NNODE * 4;
    f16* sw1 = (f16*)cur;         cur += (size_t)6 * HD * HD * 2;
    f16* sw2 = (f16*)cur;         cur += (size_t)6 * HD * HD * 2;
    f16* swme = (f16*)cur;        cur += (size_t)6 * HD * HD * 2;
    f16* swm1 = (f16*)cur;        cur += (size_t)6 * 256 * HD * 2;
    f16* swm2 = (f16*)cur;        cur += (size_t)6 * 256 * HD * 2;
    f16* swo1 = (f16*)cur;        cur += (size_t)6 * 256 * HD * 2;
    f16* swred = (f16*)cur;       cur += (size_t)3 * 256 * HD * 2;
    f16* swo2 = (f16*)cur;        cur += (size_t)6 * HD * HD * 2;

    k_winit<<<(NG * NNODE * NNODE) / 256, 256, 0, stream>>>(winner);
    k_embed_nodes<<<TOTN, 128, 0, stream>>>(x, atab, nodef, hiddenf);
    k_embed_edges<<<NEDGE, 128, 0, stream>>>(ea, btab, eftsA);
    k_winner<<<NEDGE / 256, 256, 0, stream>>>(esrc, edst, winner);
    k_wswz<<<4224, 256, 0, stream>>>(Wm1, Wm2, Wo1, Wred, Wo2, Wmlp1, Wmlp2, Wme,
                                     swm1, swm2, swo1, swred, swo2, sw1, sw2, swme);
    k_egemm<<<dim3(192, 6), 256, 0, stream>>>(eftsA, swme, emsg);
    for (int layer = 0; layer < NLAY; ++layer) {
        k_ngemm<<<dim3(12, 6), 256, 0, stream>>>(nodef, hiddenf, swm1, swm2, swo1,
                                                 bm1, bm2, bme, bmg, bo1,
                                                 msg1, msg2, o1buf, layer);
        k_pairs<<<dim3(6, NG, 24), 256, 0, stream>>>(msg1, msg2, emsg, winner,
                                                     sw1, bmlp1, sw2, bmlp2,
                                                     maxpart, layer);
        k_pr<<<24, 256, 0, stream>>>(maxpart, o1buf, swo2, bo2, lng, lnb,
                                     swred, bred, hiddenf, layer);
    }
    k_final<<<NG, 128, 0, stream>>>(hiddenf, Wp1, bp1, Wp2, bp2, (float*)d_out);
}

// Round 13
// 456.771 us; speedup vs baseline: 10.9404x; 1.2192x over previous
//
#include <hip/hip_runtime.h>
#include <cstddef>

typedef _Float16 f16;
typedef f16 f16x8 __attribute__((ext_vector_type(8)));
typedef float f32x4 __attribute__((ext_vector_type(4)));

constexpr int NG    = 16;    // graphs
constexpr int NNODE = 96;    // nodes per graph
constexpr int TOTN  = 1536;  // NG*NNODE
constexpr int HD    = 128;   // hidden
constexpr int NEDGE = 24576;
constexpr int NLAY  = 3;
constexpr int PSTR  = 17;    // padded LDS row-group stride (breaks 4-way bank conflict)

__device__ __forceinline__ f32x4 mfma16(f16x8 a, f16x8 b, f32x4 c) {
    return __builtin_amdgcn_mfma_f32_16x16x32_f16(a, b, c, 0, 0, 0);
}

// ---------------- embeddings ----------------
// node embeddings into zA f16 A-frag layout [tile96][kg32][row16][8]; kg 0..15 = node,
// kg 16..31 = hidden (zero-init here, rewritten by k_pr each layer)
__global__ void k_embed_nodes(const int* x, const float* atab, f16* zA) {
    const int v = blockIdx.x, h = threadIdx.x;  // TOTN x 128
    float s = 0.f;
    for (int c = 0; c < 9; ++c)
        s += atab[((size_t)(c * 119 + x[v * 9 + c])) * HD + h];
    const size_t base = ((size_t)(v >> 4) * 32);
    zA[((base + (h >> 3)) * 16 + (v & 15)) * 8 + (h & 7)] = (f16)s;
    zA[((base + 16 + (h >> 3)) * 16 + (v & 15)) * 8 + (h & 7)] = (f16)0.f;
}

__global__ void k_embed_edges(const int* ea, const float* btab, f16* eftsA) {
    const int e = blockIdx.x, h = threadIdx.x;  // NEDGE x 128
    float s = 0.f;
    for (int c = 0; c < 3; ++c)
        s += btab[((size_t)(c * 6 + ea[e * 3 + c])) * HD + h];
    eftsA[(((size_t)(e >> 4) * 16 + (h >> 3)) * 16 + (e & 15)) * 8 + (h & 7)] = (f16)s;
}

__global__ void k_winit(int* winner) {
    winner[blockIdx.x * 256 + threadIdx.x] = -1;  // NG*NNODE*NNODE threads
}

__global__ void k_winner(const int* esrc, const int* edst, int* winner) {
    const int e = blockIdx.x * 256 + threadIdx.x;  // NEDGE threads
    const int sg = esrc[e];
    const int g = sg / NNODE;
    const int li = sg - g * NNODE;
    const int lj = edst[e] - g * NNODE;
    atomicMax(&winner[((size_t)g * NNODE + li) * NNODE + lj], e);
}

// ------- weight swizzle: ALL weights -> f16 B-fragment order -------
__global__ void k_wswz(const float* Wm1, const float* Wm2, const float* Wo1,
                       const float* Wred, const float* Wo2, const float* W1,
                       const float* W2, const float* We,
                       f16* sm1, f16* sm2, f16* so1, f16* sred, f16* so2,
                       f16* s1, f16* s2, f16* sme) {
    const int idx = blockIdx.x * 256 + threadIdx.x;  // 1081344 threads
    const int S256 = 6 * 256 * 128;
    const int SRED = 3 * 256 * 128;
    const int S128 = 6 * 128 * 128;
    const float* src;
    f16* dst;
    int rel, sh;
    if (idx < S256)                   { src = Wm1;  dst = sm1;  rel = idx;              sh = 15; }
    else if (idx < 2 * S256)          { src = Wm2;  dst = sm2;  rel = idx - S256;       sh = 15; }
    else if (idx < 3 * S256)          { src = Wo1;  dst = so1;  rel = idx - 2 * S256;   sh = 15; }
    else if (idx < 3 * S256 + SRED)   { src = Wred; dst = sred; rel = idx - 3 * S256;   sh = 15; }
    else if (idx < 3 * S256 + SRED + S128)
        { src = Wo2; dst = so2; rel = idx - 3 * S256 - SRED; sh = 14; }
    else if (idx < 3 * S256 + SRED + 2 * S128)
        { src = W1;  dst = s1;  rel = idx - 3 * S256 - SRED - S128; sh = 14; }
    else if (idx < 3 * S256 + SRED + 3 * S128)
        { src = W2;  dst = s2;  rel = idx - 3 * S256 - SRED - 2 * S128; sh = 14; }
    else if (idx < 3 * S256 + SRED + 4 * S128)
        { src = We;  dst = sme; rel = idx - 3 * S256 - SRED - 3 * S128; sh = 14; }
    else return;
    const int mat = rel >> sh;
    const int r2 = rel & ((1 << sh) - 1);
    const int k = r2 >> 7, n = r2 & 127;
    dst[(size_t)mat * (1 << sh) + (((k >> 3) * 128 + n) << 3) + (k & 7)] = (f16)src[rel];
}

// ------- per-node GEMMs via MFMA (streaming zA): msg1' / msg2 / o1 -------
// grid (24, 6): x = 64-row tile, y = wh*2+s. K=256 from zA.
__global__ __launch_bounds__(256) void k_ngemm(
    const f16* __restrict__ zA,
    const f16* __restrict__ sm1, const f16* __restrict__ sm2, const f16* __restrict__ so1,
    const float* __restrict__ bm1, const float* __restrict__ bm2,
    const float* __restrict__ bme, const float* __restrict__ bmg,
    const float* __restrict__ bo1,
    float* __restrict__ msg1, float* __restrict__ msg2, float* __restrict__ o1buf,
    int layer) {
    const int tid = threadIdx.x, lane = tid & 63, w = tid >> 6;
    const int mr = lane & 15, q = lane >> 4;
    const int t0 = blockIdx.x;  // 64-row tile
    const int wh = blockIdx.y >> 1, s = blockIdx.y & 1, ls = layer * 2 + s;
    const f16* B;
    float* out;
    float bias[8];
    if (wh == 0) {
        B = sm1 + (size_t)ls * 32768; out = msg1 + (size_t)s * TOTN * HD;
        for (int nt = 0; nt < 8; ++nt) {
            const int col = nt * 16 + mr;
            bias[nt] = bm1[ls * HD + col] + bme[ls * HD + col] + bmg[ls * HD + col];
        }
    } else if (wh == 1) {
        B = sm2 + (size_t)ls * 32768; out = msg2 + (size_t)s * TOTN * HD;
        for (int nt = 0; nt < 8; ++nt) bias[nt] = bm2[ls * HD + nt * 16 + mr];
    } else {
        B = so1 + (size_t)ls * 32768; out = o1buf + (size_t)s * TOTN * HD;
        for (int nt = 0; nt < 8; ++nt) bias[nt] = bo1[ls * HD + nt * 16 + mr];
    }
    const size_t tIdx = (size_t)t0 * 4 + w;  // 16-row tile for this wave
    f32x4 acc[8];
#pragma unroll
    for (int nt = 0; nt < 8; ++nt) acc[nt] = (f32x4){0.f, 0.f, 0.f, 0.f};
#pragma unroll
    for (int kt = 0; kt < 8; ++kt) {
        const int kq = kt * 4 + q;
        f16x8 a = *(const f16x8*)&zA[((tIdx * 32 + kq) * 16 + mr) * 8];
        const f16* bp = B + ((size_t)kq * HD) * 8;
#pragma unroll
        for (int nt = 0; nt < 8; ++nt) {
            f16x8 bv = *(const f16x8*)(bp + (nt * 16 + mr) * 8);
            acc[nt] = mfma16(a, bv, acc[nt]);
        }
    }
#pragma unroll
    for (int nt = 0; nt < 8; ++nt) {
        const int col = nt * 16 + mr;
#pragma unroll
        for (int r = 0; r < 4; ++r) {
            const int row = t0 * 64 + w * 16 + q * 4 + r;
            out[(size_t)row * HD + col] = acc[nt][r] + bias[nt];
        }
    }
}

// ------- per-edge GEMM (ALL 6 mats): emsg = eftsA @ Wme -------
__global__ __launch_bounds__(256) void k_egemm(
    const f16* __restrict__ eftsA, const f16* __restrict__ sme,
    f16* __restrict__ emsg) {
    const int tid = threadIdx.x, lane = tid & 63, w = tid >> 6;
    const int mr = lane & 15, q = lane >> 4;
    const int ls = blockIdx.y;
    const f16* B = sme + (size_t)ls * 16384;
    f32x4 acc[2][8];
#pragma unroll
    for (int mt = 0; mt < 2; ++mt)
#pragma unroll
        for (int nt = 0; nt < 8; ++nt) acc[mt][nt] = (f32x4){0.f, 0.f, 0.f, 0.f};
#pragma unroll
    for (int kt = 0; kt < 4; ++kt) {
        const int kq = kt * 4 + q;
        f16x8 a0 = *(const f16x8*)&eftsA[(((size_t)(blockIdx.x * 8 + 2 * w + 0) * 16 + kq) * 16 + mr) * 8];
        f16x8 a1 = *(const f16x8*)&eftsA[(((size_t)(blockIdx.x * 8 + 2 * w + 1) * 16 + kq) * 16 + mr) * 8];
        const f16* bp = B + ((size_t)kq * HD) * 8;
#pragma unroll
        for (int nt = 0; nt < 8; ++nt) {
            f16x8 bv = *(const f16x8*)(bp + (nt * 16 + mr) * 8);
            acc[0][nt] = mfma16(a0, bv, acc[0][nt]);
            acc[1][nt] = mfma16(a1, bv, acc[1][nt]);
        }
    }
#pragma unroll
    for (int mt = 0; mt < 2; ++mt) {
        const int ebase = blockIdx.x * 128 + (2 * w + mt) * 16 + q * 4;
#pragma unroll
        for (int nt = 0; nt < 8; ++nt) {
            const int col = nt * 16 + mr;
#pragma unroll
            for (int r = 0; r < 4; ++r)
                emsg[((size_t)ls * NEDGE + ebase + r) * HD + col] = (f16)acc[mt][nt][r];
        }
    }
}

// ---------- pair MLP v3: B-frags in registers, n-split waves ----------
// grid (6 jt, NG, 4 zz = cp*2+s); 256 thr; 6 i-octets per block.
// Wave w owns n-tiles {2w, 2w+1} for ALL 8 m-tiles; B-fragments loaded once.
__global__ __launch_bounds__(256) void k_pairs(
    const float* __restrict__ msg1, const float* __restrict__ msg2,
    const f16* __restrict__ emsg, const int* __restrict__ winner,
    const f16* __restrict__ w1s, const float* __restrict__ bmlp1,
    const f16* __restrict__ w2s, const float* __restrict__ bmlp2,
    float* __restrict__ maxpart, int layer) {
    __shared__ __align__(16) f16 Pb[((7 * 16 + 15) * PSTR + 15) * 8 + 8];  // ~34.8 KB
    __shared__ __align__(16) f16 Qb[((7 * 16 + 15) * PSTR + 15) * 8 + 8];
    const int tid = threadIdx.x, lane = tid & 63, w = tid >> 6;
    const int mr = lane & 15, q = lane >> 4;
    const int jt = blockIdx.x, b = blockIdx.y, zz = blockIdx.z;
    const int cp = zz >> 1, s = zz & 1, ls = layer * 2 + s;
    const int j0 = jt * 16;
    const float* M1 = msg1 + ((size_t)s * TOTN + b * NNODE) * HD;
    const float* M2 = msg2 + ((size_t)s * TOTN + b * NNODE) * HD;
    const f16* EM = emsg + (size_t)ls * NEDGE * HD;
    const f16* W1 = w1s + (size_t)ls * HD * HD;
    const f16* W2 = w2s + (size_t)ls * HD * HD;
    // ---- preload B fragments for this wave's 2 n-tiles (both GEMMs) ----
    f16x8 Bf1[4][2], Bf2[4][2];
#pragma unroll
    for (int kt = 0; kt < 4; ++kt)
#pragma unroll
        for (int ntl = 0; ntl < 2; ++ntl) {
            const size_t off = ((size_t)(kt * 4 + q) * 128 + (2 * w + ntl) * 16 + mr) * 8;
            Bf1[kt][ntl] = *(const f16x8*)(W1 + off);
            Bf2[kt][ntl] = *(const f16x8*)(W2 + off);
        }
    float b1v[2], b2v[2];
#pragma unroll
    for (int ntl = 0; ntl < 2; ++ntl) {
        const int col = (2 * w + ntl) * 16 + mr;
        b1v[ntl] = bmlp1[ls * HD + col];
        b2v[ntl] = bmlp2[ls * HD + col];
    }
    float maxr[2][4];
#pragma unroll
    for (int ntl = 0; ntl < 2; ++ntl)
#pragma unroll
        for (int r = 0; r < 4; ++r) maxr[ntl][r] = -3.402823466e38f;

    const int prow = tid >> 1, half = tid & 1;
    const int pj = prow & 15, pii = prow >> 4;
    const float* m1r = M1 + (size_t)(j0 + pj) * HD + half * 64;

    for (int it = 0; it < 6; ++it) {
        const int i = cp * 48 + it * 8 + pii;
        // ---- build P = relu(msg1[j]+msg2[i]+edge) into padded A-frag layout ----
        {
            const int wv = winner[((size_t)b * NNODE + i) * NNODE + (j0 + pj)];
            const float* m2r = M2 + (size_t)i * HD + half * 64;
            const f16* er = EM + (size_t)(wv < 0 ? 0 : wv) * HD + half * 64;
#pragma unroll
            for (int c8 = 0; c8 < 64; c8 += 8) {
                float4 x0 = *(const float4*)(m1r + c8);
                float4 x1 = *(const float4*)(m1r + c8 + 4);
                float4 y0 = *(const float4*)(m2r + c8);
                float4 y1 = *(const float4*)(m2r + c8 + 4);
                float v[8] = {x0.x + y0.x, x0.y + y0.y, x0.z + y0.z, x0.w + y0.w,
                              x1.x + y1.x, x1.y + y1.y, x1.z + y1.z, x1.w + y1.w};
                if (wv >= 0) {
                    f16x8 e8 = *(const f16x8*)(er + c8);
#pragma unroll
                    for (int u = 0; u < 8; ++u) v[u] += (float)e8[u];
                }
                f16x8 pv;
#pragma unroll
                for (int u = 0; u < 8; ++u) pv[u] = (f16)fmaxf(v[u], 0.f);
                const int k = half * 64 + c8;
                *(f16x8*)&Pb[((pii * 16 + (k >> 3)) * PSTR + pj) * 8] = pv;
            }
        }
        __syncthreads();
        // ---- GEMM1: all 8 m-tiles x this wave's 2 n-tiles ----
        f32x4 acc[8][2];
#pragma unroll
        for (int mt = 0; mt < 8; ++mt)
#pragma unroll
            for (int ntl = 0; ntl < 2; ++ntl) acc[mt][ntl] = (f32x4){0.f, 0.f, 0.f, 0.f};
#pragma unroll
        for (int kt = 0; kt < 4; ++kt) {
#pragma unroll
            for (int mt = 0; mt < 8; ++mt) {
                f16x8 a = *(const f16x8*)&Pb[((mt * 16 + kt * 4 + q) * PSTR + mr) * 8];
                acc[mt][0] = mfma16(a, Bf1[kt][0], acc[mt][0]);
                acc[mt][1] = mfma16(a, Bf1[kt][1], acc[mt][1]);
            }
        }
        // ---- write Q = relu(acc + b1) into Qb ----
#pragma unroll
        for (int mt = 0; mt < 8; ++mt)
#pragma unroll
            for (int ntl = 0; ntl < 2; ++ntl) {
                const int col = (2 * w + ntl) * 16 + mr;
                const int kg = col >> 3, kj = col & 7;
#pragma unroll
                for (int r = 0; r < 4; ++r) {
                    float v = fmaxf(acc[mt][ntl][r] + b1v[ntl], 0.f);
                    Qb[((mt * 16 + kg) * PSTR + q * 4 + r) * 8 + kj] = (f16)v;
                }
            }
        __syncthreads();
        // ---- GEMM2 + running max over i (m-tiles) ----
#pragma unroll
        for (int mt = 0; mt < 8; ++mt)
#pragma unroll
            for (int ntl = 0; ntl < 2; ++ntl) acc[mt][ntl] = (f32x4){0.f, 0.f, 0.f, 0.f};
#pragma unroll
        for (int kt = 0; kt < 4; ++kt) {
#pragma unroll
            for (int mt = 0; mt < 8; ++mt) {
                f16x8 a = *(const f16x8*)&Qb[((mt * 16 + kt * 4 + q) * PSTR + mr) * 8];
                acc[mt][0] = mfma16(a, Bf2[kt][0], acc[mt][0]);
                acc[mt][1] = mfma16(a, Bf2[kt][1], acc[mt][1]);
            }
        }
#pragma unroll
        for (int ntl = 0; ntl < 2; ++ntl)
#pragma unroll
            for (int r = 0; r < 4; ++r) {
                float m0 = acc[0][ntl][r];
#pragma unroll
                for (int mt = 1; mt < 8; ++mt) m0 = fmaxf(m0, acc[mt][ntl][r]);
                maxr[ntl][r] = fmaxf(maxr[ntl][r], m0 + b2v[ntl]);
            }
        __syncthreads();  // Q reads done; also guards next iteration's P overwrite
    }
    // ---- direct write (waves own disjoint columns; rows = q*4+r) ----
#pragma unroll
    for (int ntl = 0; ntl < 2; ++ntl) {
        const int col = (2 * w + ntl) * 16 + mr;
#pragma unroll
        for (int r = 0; r < 4; ++r) {
            const int j = j0 + q * 4 + r;
            maxpart[((size_t)zz * TOTN + b * NNODE + j) * HD + col] = maxr[ntl][r];
        }
    }
}

// ---- fused MFMA: maxreduce(4 slices) -> o2 GEMM -> LN -> red GEMM -> hidden/zA ----
// grid (24); 256 thr; block = 64 node rows x 2 streams.
__global__ __launch_bounds__(256) void k_pr(
    const float* __restrict__ maxpart, const float* __restrict__ o1buf,
    const f16* __restrict__ so2, const float* __restrict__ bo2,
    const float* __restrict__ lng, const float* __restrict__ lnb,
    const f16* __restrict__ sred, const float* __restrict__ bred,
    float* __restrict__ hiddenf, f16* __restrict__ zA, int layer) {
    __shared__ __align__(16) f16 Af[16384];  // 32 KB, time-shared A1/A2
    const int tid = threadIdx.x, lane = tid & 63, w = tid >> 6;
    const int mr = lane & 15, q = lane >> 4;
    const int row0 = blockIdx.x * 64;
    {
        const int mrow = tid >> 1, half = tid & 1;
        const int sb = mrow >> 6, rl = mrow & 63;
        const int row = row0 + rl;
#pragma unroll
        for (int c8 = 0; c8 < 64; c8 += 8) {
            const int col = half * 64 + c8;
            const float* p0 = maxpart + ((size_t)(0 + sb) * TOTN + row) * HD + col;
            const float* p1 = maxpart + ((size_t)(2 + sb) * TOTN + row) * HD + col;
            float4 u0 = *(const float4*)p0;
            float4 u1 = *(const float4*)(p0 + 4);
            float4 v0 = *(const float4*)p1;
            float4 v1 = *(const float4*)(p1 + 4);
            f16x8 pv;
            pv[0] = (f16)fmaxf(u0.x, v0.x); pv[1] = (f16)fmaxf(u0.y, v0.y);
            pv[2] = (f16)fmaxf(u0.z, v0.z); pv[3] = (f16)fmaxf(u0.w, v0.w);
            pv[4] = (f16)fmaxf(u1.x, v1.x); pv[5] = (f16)fmaxf(u1.y, v1.y);
            pv[6] = (f16)fmaxf(u1.z, v1.z); pv[7] = (f16)fmaxf(u1.w, v1.w);
            *(f16x8*)&Af[(((sb * 4 + (rl >> 4)) * 16 + (col >> 3)) * 16 + (rl & 15)) * 8] = pv;
        }
    }
    __syncthreads();
    const int sw = w >> 1, ls = layer * 2 + sw;
    const f16* B1 = so2 + (size_t)ls * 16384;
    f32x4 acc[2][8];
#pragma unroll
    for (int mt = 0; mt < 2; ++mt)
#pragma unroll
        for (int nt = 0; nt < 8; ++nt) acc[mt][nt] = (f32x4){0.f, 0.f, 0.f, 0.f};
#pragma unroll
    for (int kt = 0; kt < 4; ++kt) {
        const int kq = kt * 4 + q;
        f16x8 a0 = *(const f16x8*)&Af[(((sw * 4 + (w & 1) * 2 + 0) * 16 + kq) * 16 + mr) * 8];
        f16x8 a1 = *(const f16x8*)&Af[(((sw * 4 + (w & 1) * 2 + 1) * 16 + kq) * 16 + mr) * 8];
        const f16* bp = B1 + ((size_t)kq * HD) * 8;
#pragma unroll
        for (int nt = 0; nt < 8; ++nt) {
            f16x8 bv = *(const f16x8*)(bp + (nt * 16 + mr) * 8);
            acc[0][nt] = mfma16(a0, bv, acc[0][nt]);
            acc[1][nt] = mfma16(a1, bv, acc[1][nt]);
        }
    }
    float lngv[8], lnbv[8], bo2v[8];
#pragma unroll
    for (int nt = 0; nt < 8; ++nt) {
        const int col = nt * 16 + mr;
        lngv[nt] = lng[ls * HD + col];
        lnbv[nt] = lnb[ls * HD + col];
        bo2v[nt] = bo2[ls * HD + col];
    }
#pragma unroll
    for (int mt = 0; mt < 2; ++mt) {
#pragma unroll
        for (int nt = 0; nt < 8; ++nt) {
            const int col = nt * 16 + mr;
#pragma unroll
            for (int r = 0; r < 4; ++r) {
                const int rl = (w & 1) * 32 + mt * 16 + q * 4 + r;
                float v = acc[mt][nt][r] + bo2v[nt] +
                          o1buf[((size_t)sw * TOTN + row0 + rl) * HD + col];
                acc[mt][nt][r] = fmaxf(v, 0.f);
            }
        }
#pragma unroll
        for (int r = 0; r < 4; ++r) {
            float su = 0.f, sq = 0.f;
#pragma unroll
            for (int nt = 0; nt < 8; ++nt) {
                su += acc[mt][nt][r];
                sq += acc[mt][nt][r] * acc[mt][nt][r];
            }
#pragma unroll
            for (int mask = 1; mask <= 8; mask <<= 1) {
                su += __shfl_xor(su, mask, 64);
                sq += __shfl_xor(sq, mask, 64);
            }
            const float mean = su * (1.f / 128.f);
            float var = sq * (1.f / 128.f) - mean * mean;
            var = fmaxf(var, 0.f);
            const float rstd = 1.f / sqrtf(var + 1e-5f);
#pragma unroll
            for (int nt = 0; nt < 8; ++nt)
                acc[mt][nt][r] = (acc[mt][nt][r] - mean) * rstd * lngv[nt] + lnbv[nt];
        }
    }
    __syncthreads();
#pragma unroll
    for (int mt = 0; mt < 2; ++mt)
#pragma unroll
        for (int nt = 0; nt < 8; ++nt) {
            const int kg2 = sw * 16 + nt * 2 + (mr >> 3), j2 = mr & 7;
#pragma unroll
            for (int r = 0; r < 4; ++r) {
                const int rl = (w & 1) * 32 + mt * 16 + q * 4 + r;
                Af[(((rl >> 4) * 32 + kg2) * 16 + (rl & 15)) * 8 + j2] = (f16)acc[mt][nt][r];
            }
        }
    __syncthreads();
    const f16* B2 = sred + (size_t)layer * 32768;
    f32x4 a2[8];
#pragma unroll
    for (int nt = 0; nt < 8; ++nt) a2[nt] = (f32x4){0.f, 0.f, 0.f, 0.f};
#pragma unroll
    for (int kt = 0; kt < 8; ++kt) {
        const int kq = kt * 4 + q;
        f16x8 av = *(const f16x8*)&Af[((w * 32 + kq) * 16 + mr) * 8];
        const f16* bp = B2 + ((size_t)kq * HD) * 8;
#pragma unroll
        for (int nt = 0; nt < 8; ++nt) {
            f16x8 bv = *(const f16x8*)(bp + (nt * 16 + mr) * 8);
            a2[nt] = mfma16(av, bv, a2[nt]);
        }
    }
#pragma unroll
    for (int nt = 0; nt < 8; ++nt) {
        const int col = nt * 16 + mr;
        const float bb = bred[layer * HD + col];
#pragma unroll
        for (int r = 0; r < 4; ++r) {
            const int row = row0 + w * 16 + q * 4 + r;
            const float v = a2[nt][r] + bb;
            hiddenf[(size_t)row * HD + col] = v;
            zA[(((size_t)(row >> 4) * 32 + 16 + (col >> 3)) * 16 + (row & 15)) * 8 + (col & 7)] = (f16)v;
        }
    }
}

// ---------------- mean-pool + 2-layer head; float32 output ----------------
__global__ void k_final(const float* hiddenf, const float* Wp1, const float* bp1,
                        const float* Wp2, const float* bp2, float* out) {
    __shared__ float se[128];
    __shared__ float sr[128];
    const int b = blockIdx.x, h = threadIdx.x;
    float acc = 0.f;
    for (int v = 0; v < NNODE; ++v)
        acc += hiddenf[((size_t)b * NNODE + v) * HD + h];
    se[h] = acc * (1.f / 96.f);
    __syncthreads();
    float a2 = bp1[h];
    for (int k = 0; k < 128; ++k)
        a2 += se[k] * Wp1[(size_t)k * HD + h];
    a2 = fmaxf(a2, 0.f);
    sr[h] = a2 * Wp2[h];
    __syncthreads();
    for (int off = 64; off > 0; off >>= 1) {
        if (h < off) sr[h] += sr[h + off];
        __syncthreads();
    }
    if (h == 0) out[b] = sr[0] + bp2[0];
}

extern "C" void kernel_launch(void* const* d_in, const int* in_sizes, int n_in,
                              void* d_out, int out_size, void* d_ws, size_t ws_size,
                              hipStream_t stream) {
    (void)in_sizes; (void)n_in; (void)out_size; (void)ws_size;
    const int* x    = (const int*)d_in[0];
    const int* ea   = (const int*)d_in[1];
    const int* esrc = (const int*)d_in[2];
    const int* edst = (const int*)d_in[3];
    const float* atab = (const float*)d_in[6];
    const float* btab = (const float*)d_in[7];
    const float* Wm1 = (const float*)d_in[8];    const float* bm1 = (const float*)d_in[9];
    const float* Wm2 = (const float*)d_in[10];   const float* bm2 = (const float*)d_in[11];
    const float* Wme = (const float*)d_in[12];   const float* bme = (const float*)d_in[13];
    const float* bmg = (const float*)d_in[15];
    const float* Wmlp1 = (const float*)d_in[16]; const float* bmlp1 = (const float*)d_in[17];
    const float* Wmlp2 = (const float*)d_in[18]; const float* bmlp2 = (const float*)d_in[19];
    const float* Wo1 = (const float*)d_in[20];   const float* bo1 = (const float*)d_in[21];
    const float* Wo2 = (const float*)d_in[22];   const float* bo2 = (const float*)d_in[23];
    const float* lng = (const float*)d_in[24];   const float* lnb = (const float*)d_in[25];
    const float* Wred = (const float*)d_in[26];  const float* bred = (const float*)d_in[27];
    const float* Wp1 = (const float*)d_in[28];   const float* bp1 = (const float*)d_in[29];
    const float* Wp2 = (const float*)d_in[30];   const float* bp2 = (const float*)d_in[31];

    char* cur = (char*)d_ws;
    f16* zA = (f16*)cur;          cur += (size_t)TOTN * 256 * 2;
    float* hiddenf = (float*)cur; cur += (size_t)TOTN * HD * 4;
    f16* eftsA = (f16*)cur;       cur += (size_t)NEDGE * HD * 2;
    f16* emsg = (f16*)cur;        cur += (size_t)6 * NEDGE * HD * 2;
    float* msg1 = (float*)cur;    cur += (size_t)2 * TOTN * HD * 4;
    float* msg2 = (float*)cur;    cur += (size_t)2 * TOTN * HD * 4;
    float* o1buf = (float*)cur;   cur += (size_t)2 * TOTN * HD * 4;
    float* maxpart = (float*)cur; cur += (size_t)4 * TOTN * HD * 4;
    int* winner = (int*)cur;      cur += (size_t)NG * NNODE * NNODE * 4;
    f16* sw1 = (f16*)cur;         cur += (size_t)6 * HD * HD * 2;
    f16* sw2 = (f16*)cur;         cur += (size_t)6 * HD * HD * 2;
    f16* swme = (f16*)cur;        cur += (size_t)6 * HD * HD * 2;
    f16* swm1 = (f16*)cur;        cur += (size_t)6 * 256 * HD * 2;
    f16* swm2 = (f16*)cur;        cur += (size_t)6 * 256 * HD * 2;
    f16* swo1 = (f16*)cur;        cur += (size_t)6 * 256 * HD * 2;
    f16* swred = (f16*)cur;       cur += (size_t)3 * 256 * HD * 2;
    f16* swo2 = (f16*)cur;        cur += (size_t)6 * HD * HD * 2;

    k_winit<<<(NG * NNODE * NNODE) / 256, 256, 0, stream>>>(winner);
    k_embed_nodes<<<TOTN, 128, 0, stream>>>(x, atab, zA);
    k_embed_edges<<<NEDGE, 128, 0, stream>>>(ea, btab, eftsA);
    k_winner<<<NEDGE / 256, 256, 0, stream>>>(esrc, edst, winner);
    k_wswz<<<4224, 256, 0, stream>>>(Wm1, Wm2, Wo1, Wred, Wo2, Wmlp1, Wmlp2, Wme,
                                     swm1, swm2, swo1, swred, swo2, sw1, sw2, swme);
    k_egemm<<<dim3(192, 6), 256, 0, stream>>>(eftsA, swme, emsg);
    for (int layer = 0; layer < NLAY; ++layer) {
        k_ngemm<<<dim3(24, 6), 256, 0, stream>>>(zA, swm1, swm2, swo1,
                                                 bm1, bm2, bme, bmg, bo1,
                                                 msg1, msg2, o1buf, layer);
        k_pairs<<<dim3(6, NG, 4), 256, 0, stream>>>(msg1, msg2, emsg, winner,
                                                    sw1, bmlp1, sw2, bmlp2,
                                                    maxpart, layer);
        k_pr<<<24, 256, 0, stream>>>(maxpart, o1buf, swo2, bo2, lng, lnb,
                                     swred, bred, hiddenf, zA, layer);
    }
    k_final<<<NG, 128, 0, stream>>>(hiddenf, Wp1, bp1, Wp2, bp2, (float*)d_out);
}